// Round 6
// baseline (302.037 us; speedup 1.0000x reference)
//
#include <hip/hip_runtime.h>
#include <hip/hip_bf16.h>

typedef short bf16x8 __attribute__((ext_vector_type(8)));
typedef float f32x4 __attribute__((ext_vector_type(4)));

#define BCAP 8192   // per-bucket bin capacity (mean ~4096 for E=1.6M, NB=391)

__device__ inline float bf2f(unsigned short u) {
    union { unsigned int i; float f; } v; v.i = ((unsigned int)u) << 16; return v.f;
}
__device__ inline unsigned short f2bf(float f) {
    union { float f; unsigned int i; } v; v.f = f;
    unsigned int r = v.i + 0x7FFFu + ((v.i >> 16) & 1u);
    return (unsigned short)(r >> 16);
}
__device__ inline float u_lo(unsigned u) {
    union { unsigned i; float f; } v; v.i = u << 16; return v.f;
}
__device__ inline float u_hi(unsigned u) {
    union { unsigned i; float f; } v; v.i = u & 0xFFFF0000u; return v.f;
}
__device__ inline void acc8(float* ac, uint4 v) {
    ac[0] += u_lo(v.x); ac[1] += u_hi(v.x);
    ac[2] += u_lo(v.y); ac[3] += u_hi(v.y);
    ac[4] += u_lo(v.z); ac[5] += u_hi(v.z);
    ac[6] += u_lo(v.w); ac[7] += u_hi(v.w);
}

// ---- fused setup: weight/bias conversion + bin_cnt/gctr init + flags ----
__global__ __launch_bounds__(256) void k_setup(
    const void* __restrict__ W1r, const void* __restrict__ W2r,
    const void* __restrict__ b1r, const void* __restrict__ b2r,
    const unsigned int* __restrict__ eiraw,
    unsigned short* __restrict__ Wb1, unsigned short* __restrict__ Wb2,
    float* __restrict__ bb1, float* __restrict__ bb2,
    int* __restrict__ bin_cnt, int* gctr, int* flags, int NB)
{
    __shared__ int cs, ce;
    int blk = blockIdx.x, tid = threadIdx.x;
    const unsigned short* w1u = (const unsigned short*)W1r;
    int lf = 0;
    for (int i = tid; i < 4096; i += 256) {
        unsigned e = (w1u[i] >> 7) & 0xFF;
        lf += (e >= 0x90);               // |val| >= 2^17: impossible for real bf16 weights
    }
    for (int o = 32; o; o >>= 1) lf += __shfl_down(lf, o);
    if (tid == 0) { cs = 0; ce = 0; }
    __syncthreads();
    if ((tid & 63) == 0 && lf) atomicAdd(&cs, lf);
    __syncthreads();
    bool isf32 = cs > 16;

    if (blk < 64) {
        int i = blk * 256 + tid;
        Wb1[i] = isf32 ? f2bf(((const float*)W1r)[i]) : ((const unsigned short*)W1r)[i];
    } else if (blk < 72) {
        int i = (blk - 64) * 256 + tid;
        Wb2[i] = isf32 ? f2bf(((const float*)W2r)[i]) : ((const unsigned short*)W2r)[i];
    } else if (blk == 72) {
        if (tid < 128) bb1[tid] = isf32 ? ((const float*)b1r)[tid] : bf2f(((const unsigned short*)b1r)[tid]);
        else if (tid < 144) bb2[tid - 128] = isf32 ? ((const float*)b2r)[tid - 128] : bf2f(((const unsigned short*)b2r)[tid - 128]);
    } else if (blk == 73) {
        for (int i = tid; i < NB; i += 256) bin_cnt[i] = 0;
        if (tid == 0) *gctr = 0;
    } else {                             // blk == 74: flags
        int le = 0;
        for (int i = tid; i < 128; i += 256)
            if ((i & 1) && eiraw[i] != 0) le++;
        for (int o = 32; o; o >>= 1) le += __shfl_down(le, o);
        if ((tid & 63) == 0 && le) atomicAdd(&ce, le);
        __syncthreads();
        if (tid == 0) { flags[0] = isf32 ? 1 : 0; flags[1] = (ce == 0) ? 1 : 0; }
    }
}

// ---- phase A: bin edges by dst>>8 into per-bucket regions; packed (ldst<<20)|src
__global__ __launch_bounds__(256) void k_binA(const void* __restrict__ ei,
                                              int* __restrict__ bin_cnt, int* __restrict__ bin,
                                              int E, int NB, const int* __restrict__ flags) {
    __shared__ int cnt[512];
    __shared__ int base[512];
    int tid = threadIdx.x;
    for (int i = tid; i < 512; i += 256) cnt[i] = 0;
    bool i64 = flags[1] != 0;
    long e0 = (long)blockIdx.x * 4096;
    int src[16], dst[16];
#pragma unroll
    for (int i = 0; i < 16; i++) {
        long e = e0 + i * 256 + tid;
        if (e < E) {
            if (i64) {
                src[i] = (int)((const long long*)ei)[e];
                dst[i] = (int)((const long long*)ei)[(long)E + e];
            } else {
                src[i] = ((const int*)ei)[e];
                dst[i] = ((const int*)ei)[(long)E + e];
            }
        } else dst[i] = -1;
    }
    __syncthreads();
#pragma unroll
    for (int i = 0; i < 16; i++)
        if (dst[i] >= 0) atomicAdd(&cnt[dst[i] >> 8], 1);
    __syncthreads();
    for (int b = tid; b < NB; b += 256) {
        int c = cnt[b];
        base[b] = c ? atomicAdd(&bin_cnt[b], c) : 0;
        cnt[b] = 0;
    }
    __syncthreads();
#pragma unroll
    for (int i = 0; i < 16; i++) {
        int d = dst[i];
        if (d >= 0) {
            int b = d >> 8;
            int pos = base[b] + atomicAdd(&cnt[b], 1);
            if (pos < BCAP) bin[(long)b * BCAP + pos] = ((d & 255) << 20) | src[i];
        }
    }
}

// ---- phase B: per-bucket CSR build in LDS; emits deg, row_start, dinv, adj
__global__ __launch_bounds__(256) void k_binB(const int* __restrict__ bin_cnt,
                                              const int* __restrict__ bin,
                                              int* __restrict__ deg_i, int* __restrict__ row_start,
                                              float* __restrict__ dinv, int* __restrict__ adj,
                                              int* gctr, int N) {
    __shared__ int deg[256];
    __shared__ int sm[256];
    __shared__ int cur[256];
    __shared__ int sbase;
    int b = blockIdx.x, tid = threadIdx.x;
    int cnt = min(bin_cnt[b], BCAP);
    const int* bp = bin + (long)b * BCAP;
    deg[tid] = 0;
    __syncthreads();
    for (int i = tid; i < cnt; i += 256)
        atomicAdd(&deg[bp[i] >> 20], 1);
    __syncthreads();
    int d = deg[tid];
    int val = d;
    sm[tid] = val;
    __syncthreads();
    for (int off = 1; off < 256; off <<= 1) {
        int t = (tid >= off) ? sm[tid - off] : 0;
        __syncthreads();
        val += t;
        sm[tid] = val;
        __syncthreads();
    }
    if (tid == 255) sbase = atomicAdd(gctr, val);
    __syncthreads();
    int start = sbase + val - d;
    cur[tid] = start;
    int n = (b << 8) + tid;
    if (n < N) {
        deg_i[n] = d;
        row_start[n] = start;
        dinv[n] = rsqrtf((float)(d + 1));
    }
    __syncthreads();
    for (int i = tid; i < cnt; i += 256) {
        int w = bp[i];
        int pos = atomicAdd(&cur[w >> 20], 1);
        adj[pos] = w & 0xFFFFF;
    }
}

// ---- MFMA GEMM: A[N,128] @ Wb[128,128] -> h~ = (A@W)*dinv[row], bf16
template <int CT, bool RAWA>
__global__ __launch_bounds__(256) void k_gemm(
    const void* __restrict__ A, const unsigned short* __restrict__ Wb,
    const float* __restrict__ dinv, unsigned short* __restrict__ ht, int N,
    const int* __restrict__ flags)
{
    constexpr int COLS = CT * 16;
    __shared__ unsigned short wfrag[4 * CT * 64 * 8];
    int tid = threadIdx.x;
    for (int idx = tid; idx < 4 * CT * 64; idx += 256) {
        int kc = idx / (CT * 64);
        int rem = idx % (CT * 64);
        int ct = rem / 64, l = rem % 64;
        int n = ct * 16 + (l & 15);
        int kbase = kc * 32 + (l >> 4) * 8;
        unsigned short* d = &wfrag[idx * 8];
#pragma unroll
        for (int j = 0; j < 8; j++) d[j] = Wb[(kbase + j) * COLS + n];
    }
    bool af32 = RAWA && (flags[0] != 0);
    __syncthreads();

    int wave = tid >> 6, lane = tid & 63;
    int mrow = lane & 15, kq = lane >> 4;
    long row0 = (long)blockIdx.x * 64 + wave * 16;
    long row = row0 + mrow;
    bool valid = row < N;

    f32x4 acc[CT];
#pragma unroll
    for (int ct = 0; ct < CT; ct++) acc[ct] = (f32x4){0.f, 0.f, 0.f, 0.f};

    for (int kc = 0; kc < 4; kc++) {
        bf16x8 a = {0, 0, 0, 0, 0, 0, 0, 0};
        if (valid) {
            if (af32) {
                const float* ap = (const float*)A + row * 128 + kc * 32 + kq * 8;
                float4 f0 = *(const float4*)ap;
                float4 f1 = *(const float4*)(ap + 4);
                a[0] = (short)f2bf(f0.x); a[1] = (short)f2bf(f0.y);
                a[2] = (short)f2bf(f0.z); a[3] = (short)f2bf(f0.w);
                a[4] = (short)f2bf(f1.x); a[5] = (short)f2bf(f1.y);
                a[6] = (short)f2bf(f1.z); a[7] = (short)f2bf(f1.w);
            } else {
                a = *(const bf16x8*)((const unsigned short*)A + row * 128 + kc * 32 + kq * 8);
            }
        }
#pragma unroll
        for (int ct = 0; ct < CT; ct++) {
            bf16x8 b = *(const bf16x8*)(&wfrag[((kc * CT + ct) * 64 + lane) * 8]);
            acc[ct] = __builtin_amdgcn_mfma_f32_16x16x32_bf16(a, b, acc[ct], 0, 0, 0);
        }
    }

    float dv[4];
#pragma unroll
    for (int r = 0; r < 4; r++) {
        long orow = row0 + kq * 4 + r;
        dv[r] = (orow < N) ? dinv[orow] : 0.f;
    }
#pragma unroll
    for (int ct = 0; ct < CT; ct++) {
#pragma unroll
        for (int r = 0; r < 4; r++) {
            long orow = row0 + kq * 4 + r;
            if (orow < N) {
                float v = acc[ct][r] * dv[r];
                ht[orow * COLS + ct * 16 + mrow] = f2bf(v);
            }
        }
    }
}

// ---- fused layer-1 gather + relu/bias + 128x16 W2 matvec: writes h~2 (bf16) directly
// wave per node; processes [n0, n1)
__global__ __launch_bounds__(256) void k_gather128f(
    const unsigned short* __restrict__ h1t, const int* __restrict__ row_start,
    const int* __restrict__ deg_i, const float* __restrict__ dinv,
    const float* __restrict__ bb1, const unsigned short* __restrict__ Wb2,
    const int* __restrict__ adj, unsigned short* __restrict__ h2t, int n0, int n1)
{
    __shared__ float w2l[128 * 17];        // W2 f32, stride 17 (4-way bank spread)
    int tid = threadIdx.x;
    for (int it = 0; it < 8; it++) {
        int idx = it * 256 + tid;
        w2l[(idx >> 4) * 17 + (idx & 15)] = bf2f(Wb2[idx]);
    }
    __syncthreads();

    int wave = tid >> 6, lane = tid & 63;
    int n = n0 + blockIdx.x * 4 + wave;
    if (n >= n1) return;
    int g = lane >> 4, c = lane & 15;
    int cnt = deg_i[n];
    int start = row_start[n];
    int L = cnt + 1;                       // virtual list: neighbors + self at j==cnt

    float ac[8];
#pragma unroll
    for (int k = 0; k < 8; k++) ac[k] = 0.f;

    for (int jb = 0; jb < L; jb += 64) {
        int idx = jb + lane;
        int av = (idx < cnt) ? adj[start + idx] : n;
        int take = min(L - jb, 64);
        for (int jj = 0; jj < take; jj += 8) {
            int r0 = __shfl(av, jj + g);
            int r1 = __shfl(av, jj + 4 + g);
            bool m0 = (jj + g) < take;
            bool m1 = (jj + 4 + g) < take;
            uint4 v0 = make_uint4(0, 0, 0, 0), v1 = make_uint4(0, 0, 0, 0);
            if (m0) v0 = *(const uint4*)(h1t + (long)r0 * 128 + c * 8);
            if (m1) v1 = *(const uint4*)(h1t + (long)r1 * 128 + c * 8);
            acc8(ac, v0);
            acc8(ac, v1);
        }
    }
#pragma unroll
    for (int k = 0; k < 8; k++) {
        ac[k] += __shfl_xor(ac[k], 16);
        ac[k] += __shfl_xor(ac[k], 32);
    }
    // relu(ac*dinv + b1) per lane (all 4 groups hold replicas)
    float dv = dinv[n];
    float4 bA = *(const float4*)(bb1 + c * 8);
    float4 bB = *(const float4*)(bb1 + c * 8 + 4);
    float h[8];
    h[0] = fmaxf(ac[0] * dv + bA.x, 0.f);
    h[1] = fmaxf(ac[1] * dv + bA.y, 0.f);
    h[2] = fmaxf(ac[2] * dv + bA.z, 0.f);
    h[3] = fmaxf(ac[3] * dv + bA.w, 0.f);
    h[4] = fmaxf(ac[4] * dv + bB.x, 0.f);
    h[5] = fmaxf(ac[5] * dv + bB.y, 0.f);
    h[6] = fmaxf(ac[6] * dv + bB.z, 0.f);
    h[7] = fmaxf(ac[7] * dv + bB.w, 0.f);
    // 128x16 matvec: group g computes cols g*4..g*4+3; lane covers k = c*8..c*8+7
    float o0 = 0.f, o1 = 0.f, o2 = 0.f, o3 = 0.f;
#pragma unroll
    for (int i = 0; i < 8; i++) {
        const float* wr = &w2l[(c * 8 + i) * 17 + g * 4];
        float hv = h[i];
        o0 += hv * wr[0];
        o1 += hv * wr[1];
        o2 += hv * wr[2];
        o3 += hv * wr[3];
    }
#pragma unroll
    for (int m = 1; m < 16; m <<= 1) {
        o0 += __shfl_xor(o0, m);
        o1 += __shfl_xor(o1, m);
        o2 += __shfl_xor(o2, m);
        o3 += __shfl_xor(o3, m);
    }
    if (c == 0) {
        uint2 pv;
        pv.x = (unsigned)f2bf(o0 * dv) | ((unsigned)f2bf(o1 * dv) << 16);
        pv.y = (unsigned)f2bf(o2 * dv) | ((unsigned)f2bf(o3 * dv) << 16);
        *(uint2*)(h2t + (long)n * 16 + g * 4) = pv;
    }
}

// ---- layer-2 gather + log_softmax: wave/node, uint4 loads (32 rows per wave-load)
__global__ __launch_bounds__(256) void k_gather16(
    const unsigned short* __restrict__ h2t, const int* __restrict__ row_start,
    const int* __restrict__ deg_i, const float* __restrict__ dinv,
    const float* __restrict__ bb2, const int* __restrict__ adj,
    void* __restrict__ out, int N, const int* __restrict__ flags)
{
    int tid = threadIdx.x;
    int wave = tid >> 6, lane = tid & 63;
    int n = blockIdx.x * 4 + wave;
    if (n >= N) return;
    int half = lane & 1, rg = lane >> 1;
    int cnt = deg_i[n];
    int start = row_start[n];
    int L = cnt + 1;

    float ac[8];
#pragma unroll
    for (int k = 0; k < 8; k++) ac[k] = 0.f;

    for (int jb = 0; jb < L; jb += 32) {
        int idx = jb + lane;
        int av = (lane < 32 && idx < cnt) ? adj[start + idx] : n;
        int take = min(L - jb, 32);
        int r = __shfl(av, rg);
        bool m = rg < take;
        uint4 v = make_uint4(0, 0, 0, 0);
        if (m) v = *(const uint4*)(h2t + (long)r * 16 + half * 8);
        acc8(ac, v);
    }
#pragma unroll
    for (int k = 0; k < 8; k++) {
        ac[k] += __shfl_xor(ac[k], 2);
        ac[k] += __shfl_xor(ac[k], 4);
        ac[k] += __shfl_xor(ac[k], 8);
        ac[k] += __shfl_xor(ac[k], 16);
        ac[k] += __shfl_xor(ac[k], 32);
    }
    float dv = dinv[n];
    float4 bA = *(const float4*)(bb2 + half * 8);
    float4 bB = *(const float4*)(bb2 + half * 8 + 4);
    float vv[8];
    vv[0] = ac[0] * dv + bA.x; vv[1] = ac[1] * dv + bA.y;
    vv[2] = ac[2] * dv + bA.z; vv[3] = ac[3] * dv + bA.w;
    vv[4] = ac[4] * dv + bB.x; vv[5] = ac[5] * dv + bB.y;
    vv[6] = ac[6] * dv + bB.z; vv[7] = ac[7] * dv + bB.w;
    float m8 = vv[0];
#pragma unroll
    for (int k = 1; k < 8; k++) m8 = fmaxf(m8, vv[k]);
    float m16 = fmaxf(m8, __shfl_xor(m8, 1));
    float s8 = 0.f;
#pragma unroll
    for (int k = 0; k < 8; k++) s8 += __expf(vv[k] - m16);
    float s16 = s8 + __shfl_xor(s8, 1);
    float lg = __logf(s16);
    if (lane < 2) {
        if (flags[0]) {
            float* o = (float*)out + (long)n * 16 + half * 8;
            float4 o0 = make_float4(vv[0] - m16 - lg, vv[1] - m16 - lg, vv[2] - m16 - lg, vv[3] - m16 - lg);
            float4 o1 = make_float4(vv[4] - m16 - lg, vv[5] - m16 - lg, vv[6] - m16 - lg, vv[7] - m16 - lg);
            *(float4*)o = o0;
            *(float4*)(o + 4) = o1;
        } else {
            uint4 pv;
            pv.x = (unsigned)f2bf(vv[0] - m16 - lg) | ((unsigned)f2bf(vv[1] - m16 - lg) << 16);
            pv.y = (unsigned)f2bf(vv[2] - m16 - lg) | ((unsigned)f2bf(vv[3] - m16 - lg) << 16);
            pv.z = (unsigned)f2bf(vv[4] - m16 - lg) | ((unsigned)f2bf(vv[5] - m16 - lg) << 16);
            pv.w = (unsigned)f2bf(vv[6] - m16 - lg) | ((unsigned)f2bf(vv[7] - m16 - lg) << 16);
            *(uint4*)((unsigned short*)out + (long)n * 16 + half * 8) = pv;
        }
    }
}

static inline size_t alignup(size_t x) { return (x + 255) & ~(size_t)255; }

extern "C" void kernel_launch(void* const* d_in, const int* in_sizes, int n_in,
                              void* d_out, int out_size, void* d_ws, size_t ws_size,
                              hipStream_t stream) {
    const void* xr  = d_in[0];
    const void* ei  = d_in[1];
    const void* W1r = d_in[2];
    const void* b1r = d_in[3];
    const void* W2r = d_in[4];
    const void* b2r = d_in[5];

    int N = in_sizes[0] / 128;
    int E = in_sizes[1] / 2;
    int NB = (N + 255) >> 8;

    char* w = (char*)d_ws;
    size_t off = 0;
    int*   flags = (int*)(w + off);   off += 256;      // flags[0..1]; gctr at flags[16]
    int*   gctr  = flags + 16;
    int*   deg_i = (int*)(w + off);   off = alignup(off + (size_t)N * 4);
    int*   row_start = (int*)(w + off); off = alignup(off + (size_t)N * 4);
    float* dinv  = (float*)(w + off); off = alignup(off + (size_t)N * 4);
    float* bb1   = (float*)(w + off); off = alignup(off + 128 * 4);
    float* bb2   = (float*)(w + off); off = alignup(off + 16 * 4);
    unsigned short* Wb1 = (unsigned short*)(w + off); off = alignup(off + 16384 * 2);
    unsigned short* Wb2 = (unsigned short*)(w + off); off = alignup(off + 2048 * 2);
    int*   bin_cnt = (int*)(w + off); off = alignup(off + (size_t)NB * 4);
    int*   adj   = (int*)(w + off);   off = alignup(off + (size_t)E * 4);
    unsigned short* h1t = (unsigned short*)(w + off); off = alignup(off + (size_t)N * 128 * 2);
    unsigned short* binreg = (unsigned short*)(w + off); off = alignup(off + (size_t)N * 128 * 2);
    unsigned short* h2t = (unsigned short*)(w + off); off = alignup(off + (size_t)N * 16 * 2);
    int* bin = (int*)binreg;   // bin (NB*BCAP*4 = 12.8 MB) lives in its own scratch region

    int gG = (N + 63) / 64;
    int gA = (E + 4095) / 4096;
    int mid = (N + 1) / 2;
    int gH1 = (mid + 3) / 4;
    int gH2 = (N - mid + 3) / 4;
    int gW = (N + 3) / 4;

    k_setup<<<75, 256, 0, stream>>>(W1r, W2r, b1r, b2r, (const unsigned int*)ei,
                                    Wb1, Wb2, bb1, bb2, bin_cnt, gctr, flags, NB);
    k_binA<<<gA, 256, 0, stream>>>(ei, bin_cnt, bin, E, NB, flags);
    k_binB<<<NB, 256, 0, stream>>>(bin_cnt, bin, deg_i, row_start, dinv, adj, gctr, N);

    k_gemm<8, true><<<gG, 256, 0, stream>>>(xr, Wb1, dinv, h1t, N, flags);
    k_gather128f<<<gH1, 256, 0, stream>>>(h1t, row_start, deg_i, dinv, bb1, Wb2, adj, h2t, 0, mid);
    k_gather128f<<<gH2, 256, 0, stream>>>(h1t, row_start, deg_i, dinv, bb1, Wb2, adj, h2t, mid, N);

    k_gather16<<<gW, 256, 0, stream>>>(h2t, row_start, deg_i, dinv, bb2, adj, d_out, N, flags);
}

// Round 7
// 262.909 us; speedup vs baseline: 1.1488x; 1.1488x over previous
//
#include <hip/hip_runtime.h>
#include <hip/hip_bf16.h>

typedef short bf16x8 __attribute__((ext_vector_type(8)));
typedef float f32x4 __attribute__((ext_vector_type(4)));

#define BCAP 8192   // per-bucket bin capacity (mean ~4096 for E=1.6M, NB=391)

__device__ inline float bf2f(unsigned short u) {
    union { unsigned int i; float f; } v; v.i = ((unsigned int)u) << 16; return v.f;
}
__device__ inline unsigned short f2bf(float f) {
    union { float f; unsigned int i; } v; v.f = f;
    unsigned int r = v.i + 0x7FFFu + ((v.i >> 16) & 1u);
    return (unsigned short)(r >> 16);
}
__device__ inline float u_lo(unsigned u) {
    union { unsigned i; float f; } v; v.i = u << 16; return v.f;
}
__device__ inline float u_hi(unsigned u) {
    union { unsigned i; float f; } v; v.i = u & 0xFFFF0000u; return v.f;
}
__device__ inline void acc8(float* ac, uint4 v) {
    ac[0] += u_lo(v.x); ac[1] += u_hi(v.x);
    ac[2] += u_lo(v.y); ac[3] += u_hi(v.y);
    ac[4] += u_lo(v.z); ac[5] += u_hi(v.z);
    ac[6] += u_lo(v.w); ac[7] += u_hi(v.w);
}

// ---- fused setup: weight/bias conversion + bin_cnt/gctr init + flags ----
__global__ __launch_bounds__(256) void k_setup(
    const void* __restrict__ W1r, const void* __restrict__ W2r,
    const void* __restrict__ b1r, const void* __restrict__ b2r,
    const unsigned int* __restrict__ eiraw,
    unsigned short* __restrict__ Wb1, unsigned short* __restrict__ Wb2,
    float* __restrict__ bb1, float* __restrict__ bb2,
    int* __restrict__ bin_cnt, int* gctr, int* flags, int NB)
{
    __shared__ int cs, ce;
    int blk = blockIdx.x, tid = threadIdx.x;
    const unsigned short* w1u = (const unsigned short*)W1r;
    int lf = 0;
    for (int i = tid; i < 4096; i += 256) {
        unsigned e = (w1u[i] >> 7) & 0xFF;
        lf += (e >= 0x90);               // |val| >= 2^17: impossible for real bf16 weights
    }
    for (int o = 32; o; o >>= 1) lf += __shfl_down(lf, o);
    if (tid == 0) { cs = 0; ce = 0; }
    __syncthreads();
    if ((tid & 63) == 0 && lf) atomicAdd(&cs, lf);
    __syncthreads();
    bool isf32 = cs > 16;

    if (blk < 64) {
        int i = blk * 256 + tid;
        Wb1[i] = isf32 ? f2bf(((const float*)W1r)[i]) : ((const unsigned short*)W1r)[i];
    } else if (blk < 72) {
        int i = (blk - 64) * 256 + tid;
        Wb2[i] = isf32 ? f2bf(((const float*)W2r)[i]) : ((const unsigned short*)W2r)[i];
    } else if (blk == 72) {
        if (tid < 128) bb1[tid] = isf32 ? ((const float*)b1r)[tid] : bf2f(((const unsigned short*)b1r)[tid]);
        else if (tid < 144) bb2[tid - 128] = isf32 ? ((const float*)b2r)[tid - 128] : bf2f(((const unsigned short*)b2r)[tid - 128]);
    } else if (blk == 73) {
        for (int i = tid; i < NB; i += 256) bin_cnt[i] = 0;
        if (tid == 0) *gctr = 0;
    } else {                             // blk == 74: flags
        int le = 0;
        for (int i = tid; i < 128; i += 256)
            if ((i & 1) && eiraw[i] != 0) le++;
        for (int o = 32; o; o >>= 1) le += __shfl_down(le, o);
        if ((tid & 63) == 0 && le) atomicAdd(&ce, le);
        __syncthreads();
        if (tid == 0) { flags[0] = isf32 ? 1 : 0; flags[1] = (ce == 0) ? 1 : 0; }
    }
}

// ---- phase A: bin edges by dst>>8 into per-bucket regions; packed (ldst<<20)|src
__global__ __launch_bounds__(256) void k_binA(const void* __restrict__ ei,
                                              int* __restrict__ bin_cnt, int* __restrict__ bin,
                                              int E, int NB, const int* __restrict__ flags) {
    __shared__ int cnt[512];
    __shared__ int base[512];
    int tid = threadIdx.x;
    for (int i = tid; i < 512; i += 256) cnt[i] = 0;
    bool i64 = flags[1] != 0;
    long e0 = (long)blockIdx.x * 4096;
    int src[16], dst[16];
#pragma unroll
    for (int i = 0; i < 16; i++) {
        long e = e0 + i * 256 + tid;
        if (e < E) {
            if (i64) {
                src[i] = (int)((const long long*)ei)[e];
                dst[i] = (int)((const long long*)ei)[(long)E + e];
            } else {
                src[i] = ((const int*)ei)[e];
                dst[i] = ((const int*)ei)[(long)E + e];
            }
        } else dst[i] = -1;
    }
    __syncthreads();
#pragma unroll
    for (int i = 0; i < 16; i++)
        if (dst[i] >= 0) atomicAdd(&cnt[dst[i] >> 8], 1);
    __syncthreads();
    for (int b = tid; b < NB; b += 256) {
        int c = cnt[b];
        base[b] = c ? atomicAdd(&bin_cnt[b], c) : 0;
        cnt[b] = 0;
    }
    __syncthreads();
#pragma unroll
    for (int i = 0; i < 16; i++) {
        int d = dst[i];
        if (d >= 0) {
            int b = d >> 8;
            int pos = base[b] + atomicAdd(&cnt[b], 1);
            if (pos < BCAP) bin[(long)b * BCAP + pos] = ((d & 255) << 20) | src[i];
        }
    }
}

// ---- phase B: per-bucket CSR build in LDS; emits deg, row_start, dinv, adj
__global__ __launch_bounds__(256) void k_binB(const int* __restrict__ bin_cnt,
                                              const int* __restrict__ bin,
                                              int* __restrict__ deg_i, int* __restrict__ row_start,
                                              float* __restrict__ dinv, int* __restrict__ adj,
                                              int* gctr, int N) {
    __shared__ int deg[256];
    __shared__ int sm[256];
    __shared__ int cur[256];
    __shared__ int sbase;
    int b = blockIdx.x, tid = threadIdx.x;
    int cnt = min(bin_cnt[b], BCAP);
    const int* bp = bin + (long)b * BCAP;
    deg[tid] = 0;
    __syncthreads();
    for (int i = tid; i < cnt; i += 256)
        atomicAdd(&deg[bp[i] >> 20], 1);
    __syncthreads();
    int d = deg[tid];
    int val = d;
    sm[tid] = val;
    __syncthreads();
    for (int off = 1; off < 256; off <<= 1) {
        int t = (tid >= off) ? sm[tid - off] : 0;
        __syncthreads();
        val += t;
        sm[tid] = val;
        __syncthreads();
    }
    if (tid == 255) sbase = atomicAdd(gctr, val);
    __syncthreads();
    int start = sbase + val - d;
    cur[tid] = start;
    int n = (b << 8) + tid;
    if (n < N) {
        deg_i[n] = d;
        row_start[n] = start;
        dinv[n] = rsqrtf((float)(d + 1));
    }
    __syncthreads();
    for (int i = tid; i < cnt; i += 256) {
        int w = bp[i];
        int pos = atomicAdd(&cur[w >> 20], 1);
        adj[pos] = w & 0xFFFFF;
    }
}

// ---- MFMA GEMM: A[N,128] @ Wb[128,128] -> h~ = (A@W)*dinv[row], bf16
template <int CT, bool RAWA>
__global__ __launch_bounds__(256) void k_gemm(
    const void* __restrict__ A, const unsigned short* __restrict__ Wb,
    const float* __restrict__ dinv, unsigned short* __restrict__ ht, int N,
    const int* __restrict__ flags)
{
    constexpr int COLS = CT * 16;
    __shared__ unsigned short wfrag[4 * CT * 64 * 8];
    int tid = threadIdx.x;
    for (int idx = tid; idx < 4 * CT * 64; idx += 256) {
        int kc = idx / (CT * 64);
        int rem = idx % (CT * 64);
        int ct = rem / 64, l = rem % 64;
        int n = ct * 16 + (l & 15);
        int kbase = kc * 32 + (l >> 4) * 8;
        unsigned short* d = &wfrag[idx * 8];
#pragma unroll
        for (int j = 0; j < 8; j++) d[j] = Wb[(kbase + j) * COLS + n];
    }
    bool af32 = RAWA && (flags[0] != 0);
    __syncthreads();

    int wave = tid >> 6, lane = tid & 63;
    int mrow = lane & 15, kq = lane >> 4;
    long row0 = (long)blockIdx.x * 64 + wave * 16;
    long row = row0 + mrow;
    bool valid = row < N;

    f32x4 acc[CT];
#pragma unroll
    for (int ct = 0; ct < CT; ct++) acc[ct] = (f32x4){0.f, 0.f, 0.f, 0.f};

    for (int kc = 0; kc < 4; kc++) {
        bf16x8 a = {0, 0, 0, 0, 0, 0, 0, 0};
        if (valid) {
            if (af32) {
                const float* ap = (const float*)A + row * 128 + kc * 32 + kq * 8;
                float4 f0 = *(const float4*)ap;
                float4 f1 = *(const float4*)(ap + 4);
                a[0] = (short)f2bf(f0.x); a[1] = (short)f2bf(f0.y);
                a[2] = (short)f2bf(f0.z); a[3] = (short)f2bf(f0.w);
                a[4] = (short)f2bf(f1.x); a[5] = (short)f2bf(f1.y);
                a[6] = (short)f2bf(f1.z); a[7] = (short)f2bf(f1.w);
            } else {
                a = *(const bf16x8*)((const unsigned short*)A + row * 128 + kc * 32 + kq * 8);
            }
        }
#pragma unroll
        for (int ct = 0; ct < CT; ct++) {
            bf16x8 b = *(const bf16x8*)(&wfrag[((kc * CT + ct) * 64 + lane) * 8]);
            acc[ct] = __builtin_amdgcn_mfma_f32_16x16x32_bf16(a, b, acc[ct], 0, 0, 0);
        }
    }

    float dv[4];
#pragma unroll
    for (int r = 0; r < 4; r++) {
        long orow = row0 + kq * 4 + r;
        dv[r] = (orow < N) ? dinv[orow] : 0.f;
    }
#pragma unroll
    for (int ct = 0; ct < CT; ct++) {
#pragma unroll
        for (int r = 0; r < 4; r++) {
            long orow = row0 + kq * 4 + r;
            if (orow < N) {
                float v = acc[ct][r] * dv[r];
                ht[orow * COLS + ct * 16 + mrow] = f2bf(v);
            }
        }
    }
}

// ---- fused layer-1 gather + relu/bias + 128x16 W2 matvec -> h~2 (bf16)
// 16 nodes per block: 4 waves x 4 nodes (outer loop amortizes W2 staging)
__global__ __launch_bounds__(256) void k_gather128f(
    const unsigned short* __restrict__ h1t, const int* __restrict__ row_start,
    const int* __restrict__ deg_i, const float* __restrict__ dinv,
    const float* __restrict__ bb1, const unsigned short* __restrict__ Wb2,
    const int* __restrict__ adj, unsigned short* __restrict__ h2t, int N)
{
    __shared__ float w2l[128 * 17];        // W2 f32, stride 17 (bank spread)
    int tid = threadIdx.x;
    for (int it = 0; it < 8; it++) {
        int idx = it * 256 + tid;
        w2l[(idx >> 4) * 17 + (idx & 15)] = bf2f(Wb2[idx]);
    }
    __syncthreads();

    int wave = tid >> 6, lane = tid & 63;
    int g = lane >> 4, c = lane & 15;
    float4 bA = *(const float4*)(bb1 + c * 8);
    float4 bB = *(const float4*)(bb1 + c * 8 + 4);

    for (int it = 0; it < 4; it++) {
        int n = blockIdx.x * 16 + wave * 4 + it;
        if (n >= N) break;                 // wave-uniform
        int cnt = deg_i[n];
        int start = row_start[n];
        int L = cnt + 1;                   // virtual list: neighbors + self at j==cnt

        float ac[8];
#pragma unroll
        for (int k = 0; k < 8; k++) ac[k] = 0.f;

        for (int jb = 0; jb < L; jb += 64) {
            int idx = jb + lane;
            int av = (idx < cnt) ? adj[start + idx] : n;
            int take = min(L - jb, 64);
            for (int jj = 0; jj < take; jj += 8) {
                int r0 = __shfl(av, jj + g);
                int r1 = __shfl(av, jj + 4 + g);
                bool m0 = (jj + g) < take;
                bool m1 = (jj + 4 + g) < take;
                uint4 v0 = make_uint4(0, 0, 0, 0), v1 = make_uint4(0, 0, 0, 0);
                if (m0) v0 = *(const uint4*)(h1t + (long)r0 * 128 + c * 8);
                if (m1) v1 = *(const uint4*)(h1t + (long)r1 * 128 + c * 8);
                acc8(ac, v0);
                acc8(ac, v1);
            }
        }
#pragma unroll
        for (int k = 0; k < 8; k++) {
            ac[k] += __shfl_xor(ac[k], 16);
            ac[k] += __shfl_xor(ac[k], 32);
        }
        float dv = dinv[n];
        float h[8];
        h[0] = fmaxf(ac[0] * dv + bA.x, 0.f);
        h[1] = fmaxf(ac[1] * dv + bA.y, 0.f);
        h[2] = fmaxf(ac[2] * dv + bA.z, 0.f);
        h[3] = fmaxf(ac[3] * dv + bA.w, 0.f);
        h[4] = fmaxf(ac[4] * dv + bB.x, 0.f);
        h[5] = fmaxf(ac[5] * dv + bB.y, 0.f);
        h[6] = fmaxf(ac[6] * dv + bB.z, 0.f);
        h[7] = fmaxf(ac[7] * dv + bB.w, 0.f);
        // 128x16 matvec: group g computes cols g*4..g*4+3; lane covers k = c*8..c*8+7
        float o0 = 0.f, o1 = 0.f, o2 = 0.f, o3 = 0.f;
#pragma unroll
        for (int i = 0; i < 8; i++) {
            const float* wr = &w2l[(c * 8 + i) * 17 + g * 4];
            float hv = h[i];
            o0 += hv * wr[0];
            o1 += hv * wr[1];
            o2 += hv * wr[2];
            o3 += hv * wr[3];
        }
#pragma unroll
        for (int m = 1; m < 16; m <<= 1) {
            o0 += __shfl_xor(o0, m);
            o1 += __shfl_xor(o1, m);
            o2 += __shfl_xor(o2, m);
            o3 += __shfl_xor(o3, m);
        }
        if (c == 0) {
            uint2 pv;
            pv.x = (unsigned)f2bf(o0 * dv) | ((unsigned)f2bf(o1 * dv) << 16);
            pv.y = (unsigned)f2bf(o2 * dv) | ((unsigned)f2bf(o3 * dv) << 16);
            *(uint2*)(h2t + (long)n * 16 + g * 4) = pv;
        }
    }
}

// ---- layer-2 gather + log_softmax: one node per LANE-PAIR (32 nodes/wave)
__global__ __launch_bounds__(256) void k_gather16(
    const unsigned short* __restrict__ h2t, const int* __restrict__ row_start,
    const int* __restrict__ deg_i, const float* __restrict__ dinv,
    const float* __restrict__ bb2, const int* __restrict__ adj,
    void* __restrict__ out, int N, const int* __restrict__ flags)
{
    int tid = threadIdx.x;
    int wave = tid >> 6, lane = tid & 63;
    int half = lane & 1;
    int n = (blockIdx.x * 4 + wave) * 32 + (lane >> 1);
    bool valid = n < N;
    int cnt = valid ? deg_i[n] : 0;
    int start = valid ? row_start[n] : 0;

    float ac[8];
#pragma unroll
    for (int k = 0; k < 8; k++) ac[k] = 0.f;

    int j = 0;
    for (; j + 2 <= cnt; j += 2) {
        int s0 = adj[start + j];
        int s1 = adj[start + j + 1];
        uint4 v0 = *(const uint4*)(h2t + (long)s0 * 16 + half * 8);
        uint4 v1 = *(const uint4*)(h2t + (long)s1 * 16 + half * 8);
        acc8(ac, v0);
        acc8(ac, v1);
    }
    if (j < cnt) {
        int s = adj[start + j];
        uint4 v = *(const uint4*)(h2t + (long)s * 16 + half * 8);
        acc8(ac, v);
    }
    if (!valid) return;
    {   // self-loop
        uint4 v = *(const uint4*)(h2t + (long)n * 16 + half * 8);
        acc8(ac, v);
    }
    float dv = dinv[n];
    float4 bA = *(const float4*)(bb2 + half * 8);
    float4 bB = *(const float4*)(bb2 + half * 8 + 4);
    float vv[8];
    vv[0] = ac[0] * dv + bA.x; vv[1] = ac[1] * dv + bA.y;
    vv[2] = ac[2] * dv + bA.z; vv[3] = ac[3] * dv + bA.w;
    vv[4] = ac[4] * dv + bB.x; vv[5] = ac[5] * dv + bB.y;
    vv[6] = ac[6] * dv + bB.z; vv[7] = ac[7] * dv + bB.w;
    float m8 = vv[0];
#pragma unroll
    for (int k = 1; k < 8; k++) m8 = fmaxf(m8, vv[k]);
    float m16 = fmaxf(m8, __shfl_xor(m8, 1));   // partner = other half of same node
    float s8 = 0.f;
#pragma unroll
    for (int k = 0; k < 8; k++) s8 += __expf(vv[k] - m16);
    float s16 = s8 + __shfl_xor(s8, 1);
    float lg = __logf(s16);
    if (flags[0]) {
        float* o = (float*)out + (long)n * 16 + half * 8;
        *(float4*)o = make_float4(vv[0] - m16 - lg, vv[1] - m16 - lg, vv[2] - m16 - lg, vv[3] - m16 - lg);
        *(float4*)(o + 4) = make_float4(vv[4] - m16 - lg, vv[5] - m16 - lg, vv[6] - m16 - lg, vv[7] - m16 - lg);
    } else {
        uint4 pv;
        pv.x = (unsigned)f2bf(vv[0] - m16 - lg) | ((unsigned)f2bf(vv[1] - m16 - lg) << 16);
        pv.y = (unsigned)f2bf(vv[2] - m16 - lg) | ((unsigned)f2bf(vv[3] - m16 - lg) << 16);
        pv.z = (unsigned)f2bf(vv[4] - m16 - lg) | ((unsigned)f2bf(vv[5] - m16 - lg) << 16);
        pv.w = (unsigned)f2bf(vv[6] - m16 - lg) | ((unsigned)f2bf(vv[7] - m16 - lg) << 16);
        *(uint4*)((unsigned short*)out + (long)n * 16 + half * 8) = pv;
    }
}

static inline size_t alignup(size_t x) { return (x + 255) & ~(size_t)255; }

extern "C" void kernel_launch(void* const* d_in, const int* in_sizes, int n_in,
                              void* d_out, int out_size, void* d_ws, size_t ws_size,
                              hipStream_t stream) {
    const void* xr  = d_in[0];
    const void* ei  = d_in[1];
    const void* W1r = d_in[2];
    const void* b1r = d_in[3];
    const void* W2r = d_in[4];
    const void* b2r = d_in[5];

    int N = in_sizes[0] / 128;
    int E = in_sizes[1] / 2;
    int NB = (N + 255) >> 8;

    char* w = (char*)d_ws;
    size_t off = 0;
    int*   flags = (int*)(w + off);   off += 256;      // flags[0..1]; gctr at flags[16]
    int*   gctr  = flags + 16;
    int*   deg_i = (int*)(w + off);   off = alignup(off + (size_t)N * 4);
    int*   row_start = (int*)(w + off); off = alignup(off + (size_t)N * 4);
    float* dinv  = (float*)(w + off); off = alignup(off + (size_t)N * 4);
    float* bb1   = (float*)(w + off); off = alignup(off + 128 * 4);
    float* bb2   = (float*)(w + off); off = alignup(off + 16 * 4);
    unsigned short* Wb1 = (unsigned short*)(w + off); off = alignup(off + 16384 * 2);
    unsigned short* Wb2 = (unsigned short*)(w + off); off = alignup(off + 2048 * 2);
    int*   bin_cnt = (int*)(w + off); off = alignup(off + (size_t)NB * 4);
    int*   adj   = (int*)(w + off);   off = alignup(off + (size_t)E * 4);
    unsigned short* h1t = (unsigned short*)(w + off); off = alignup(off + (size_t)N * 128 * 2);
    unsigned short* binreg = (unsigned short*)(w + off); off = alignup(off + (size_t)N * 128 * 2);
    unsigned short* h2t = (unsigned short*)(w + off); off = alignup(off + (size_t)N * 16 * 2);
    int* bin = (int*)binreg;   // bin (NB*BCAP*4 = 12.8 MB) in its own scratch region

    int gG = (N + 63) / 64;
    int gA = (E + 4095) / 4096;
    int gF = (N + 15) / 16;
    int gP = (N + 127) / 128;   // gather16: 128 nodes per block (4 waves x 32)

    k_setup<<<75, 256, 0, stream>>>(W1r, W2r, b1r, b2r, (const unsigned int*)ei,
                                    Wb1, Wb2, bb1, bb2, bin_cnt, gctr, flags, NB);
    k_binA<<<gA, 256, 0, stream>>>(ei, bin_cnt, bin, E, NB, flags);
    k_binB<<<NB, 256, 0, stream>>>(bin_cnt, bin, deg_i, row_start, dinv, adj, gctr, N);

    k_gemm<8, true><<<gG, 256, 0, stream>>>(xr, Wb1, dinv, h1t, N, flags);
    k_gather128f<<<gF, 256, 0, stream>>>(h1t, row_start, deg_i, dinv, bb1, Wb2, adj, h2t, N);

    k_gather16<<<gP, 256, 0, stream>>>(h2t, row_start, deg_i, dinv, bb2, adj, d_out, N, flags);
}

// Round 8
// 245.933 us; speedup vs baseline: 1.2281x; 1.0690x over previous
//
#include <hip/hip_runtime.h>
#include <hip/hip_bf16.h>

typedef short bf16x8 __attribute__((ext_vector_type(8)));
typedef float f32x4 __attribute__((ext_vector_type(4)));

#define BCAP 8192   // per-bucket bin capacity (mean ~4096 for E=1.6M, NB=391)

__device__ inline float bf2f(unsigned short u) {
    union { unsigned int i; float f; } v; v.i = ((unsigned int)u) << 16; return v.f;
}
__device__ inline unsigned short f2bf(float f) {
    union { float f; unsigned int i; } v; v.f = f;
    unsigned int r = v.i + 0x7FFFu + ((v.i >> 16) & 1u);
    return (unsigned short)(r >> 16);
}
__device__ inline float u_lo(unsigned u) {
    union { unsigned i; float f; } v; v.i = u << 16; return v.f;
}
__device__ inline float u_hi(unsigned u) {
    union { unsigned i; float f; } v; v.i = u & 0xFFFF0000u; return v.f;
}
__device__ inline void acc8(float* ac, uint4 v) {
    ac[0] += u_lo(v.x); ac[1] += u_hi(v.x);
    ac[2] += u_lo(v.y); ac[3] += u_hi(v.y);
    ac[4] += u_lo(v.z); ac[5] += u_hi(v.z);
    ac[6] += u_lo(v.w); ac[7] += u_hi(v.w);
}

// ---- fused setup: weight/bias conversion + bin_cnt/gctr init + flags ----
__global__ __launch_bounds__(256) void k_setup(
    const void* __restrict__ W1r, const void* __restrict__ W2r,
    const void* __restrict__ b1r, const void* __restrict__ b2r,
    const unsigned int* __restrict__ eiraw,
    unsigned short* __restrict__ Wb1, unsigned short* __restrict__ Wb2,
    float* __restrict__ bb1, float* __restrict__ bb2,
    int* __restrict__ bin_cnt, int* gctr, int* flags, int NB)
{
    __shared__ int cs, ce;
    int blk = blockIdx.x, tid = threadIdx.x;
    const unsigned short* w1u = (const unsigned short*)W1r;
    int lf = 0;
    for (int i = tid; i < 4096; i += 256) {
        unsigned e = (w1u[i] >> 7) & 0xFF;
        lf += (e >= 0x90);               // |val| >= 2^17: impossible for real bf16 weights
    }
    for (int o = 32; o; o >>= 1) lf += __shfl_down(lf, o);
    if (tid == 0) { cs = 0; ce = 0; }
    __syncthreads();
    if ((tid & 63) == 0 && lf) atomicAdd(&cs, lf);
    __syncthreads();
    bool isf32 = cs > 16;

    if (blk < 64) {
        int i = blk * 256 + tid;
        Wb1[i] = isf32 ? f2bf(((const float*)W1r)[i]) : ((const unsigned short*)W1r)[i];
    } else if (blk < 72) {
        int i = (blk - 64) * 256 + tid;
        Wb2[i] = isf32 ? f2bf(((const float*)W2r)[i]) : ((const unsigned short*)W2r)[i];
    } else if (blk == 72) {
        if (tid < 128) bb1[tid] = isf32 ? ((const float*)b1r)[tid] : bf2f(((const unsigned short*)b1r)[tid]);
        else if (tid < 144) bb2[tid - 128] = isf32 ? ((const float*)b2r)[tid - 128] : bf2f(((const unsigned short*)b2r)[tid - 128]);
    } else if (blk == 73) {
        for (int i = tid; i < NB; i += 256) bin_cnt[i] = 0;
        if (tid == 0) *gctr = 0;
    } else {                             // blk == 74: flags
        int le = 0;
        for (int i = tid; i < 128; i += 256)
            if ((i & 1) && eiraw[i] != 0) le++;
        for (int o = 32; o; o >>= 1) le += __shfl_down(le, o);
        if ((tid & 63) == 0 && le) atomicAdd(&ce, le);
        __syncthreads();
        if (tid == 0) { flags[0] = isf32 ? 1 : 0; flags[1] = (ce == 0) ? 1 : 0; }
    }
}

// ---- phase A: bin edges by dst>>8 into per-bucket regions; packed (ldst<<20)|src
__global__ __launch_bounds__(256) void k_binA(const void* __restrict__ ei,
                                              int* __restrict__ bin_cnt, int* __restrict__ bin,
                                              int E, int NB, const int* __restrict__ flags) {
    __shared__ int cnt[512];
    __shared__ int base[512];
    int tid = threadIdx.x;
    for (int i = tid; i < 512; i += 256) cnt[i] = 0;
    bool i64 = flags[1] != 0;
    long e0 = (long)blockIdx.x * 4096;
    int src[16], dst[16];
#pragma unroll
    for (int i = 0; i < 16; i++) {
        long e = e0 + i * 256 + tid;
        if (e < E) {
            if (i64) {
                src[i] = (int)((const long long*)ei)[e];
                dst[i] = (int)((const long long*)ei)[(long)E + e];
            } else {
                src[i] = ((const int*)ei)[e];
                dst[i] = ((const int*)ei)[(long)E + e];
            }
        } else dst[i] = -1;
    }
    __syncthreads();
#pragma unroll
    for (int i = 0; i < 16; i++)
        if (dst[i] >= 0) atomicAdd(&cnt[dst[i] >> 8], 1);
    __syncthreads();
    for (int b = tid; b < NB; b += 256) {
        int c = cnt[b];
        base[b] = c ? atomicAdd(&bin_cnt[b], c) : 0;
        cnt[b] = 0;
    }
    __syncthreads();
#pragma unroll
    for (int i = 0; i < 16; i++) {
        int d = dst[i];
        if (d >= 0) {
            int b = d >> 8;
            int pos = base[b] + atomicAdd(&cnt[b], 1);
            if (pos < BCAP) bin[(long)b * BCAP + pos] = ((d & 255) << 20) | src[i];
        }
    }
}

// ---- phase B: per-bucket CSR build in LDS; emits deg, row_start, dinv, adj
__global__ __launch_bounds__(256) void k_binB(const int* __restrict__ bin_cnt,
                                              const int* __restrict__ bin,
                                              int* __restrict__ deg_i, int* __restrict__ row_start,
                                              float* __restrict__ dinv, int* __restrict__ adj,
                                              int* gctr, int N) {
    __shared__ int deg[256];
    __shared__ int sm[256];
    __shared__ int cur[256];
    __shared__ int sbase;
    int b = blockIdx.x, tid = threadIdx.x;
    int cnt = min(bin_cnt[b], BCAP);
    const int* bp = bin + (long)b * BCAP;
    deg[tid] = 0;
    __syncthreads();
    for (int i = tid; i < cnt; i += 256)
        atomicAdd(&deg[bp[i] >> 20], 1);
    __syncthreads();
    int d = deg[tid];
    int val = d;
    sm[tid] = val;
    __syncthreads();
    for (int off = 1; off < 256; off <<= 1) {
        int t = (tid >= off) ? sm[tid - off] : 0;
        __syncthreads();
        val += t;
        sm[tid] = val;
        __syncthreads();
    }
    if (tid == 255) sbase = atomicAdd(gctr, val);
    __syncthreads();
    int start = sbase + val - d;
    cur[tid] = start;
    int n = (b << 8) + tid;
    if (n < N) {
        deg_i[n] = d;
        row_start[n] = start;
        dinv[n] = rsqrtf((float)(d + 1));
    }
    __syncthreads();
    for (int i = tid; i < cnt; i += 256) {
        int w = bp[i];
        int pos = atomicAdd(&cur[w >> 20], 1);
        adj[pos] = w & 0xFFFFF;
    }
}

// ---- MFMA GEMM: A[N,128] @ Wb[128,CT*16] -> h~ = (A@W)*dinv[row], bf16
template <int CT, bool RAWA>
__global__ __launch_bounds__(256) void k_gemm(
    const void* __restrict__ A, const unsigned short* __restrict__ Wb,
    const float* __restrict__ dinv, unsigned short* __restrict__ ht, int N,
    const int* __restrict__ flags)
{
    constexpr int COLS = CT * 16;
    __shared__ unsigned short wfrag[4 * CT * 64 * 8];
    int tid = threadIdx.x;
    for (int idx = tid; idx < 4 * CT * 64; idx += 256) {
        int kc = idx / (CT * 64);
        int rem = idx % (CT * 64);
        int ct = rem / 64, l = rem % 64;
        int n = ct * 16 + (l & 15);
        int kbase = kc * 32 + (l >> 4) * 8;
        unsigned short* d = &wfrag[idx * 8];
#pragma unroll
        for (int j = 0; j < 8; j++) d[j] = Wb[(kbase + j) * COLS + n];
    }
    bool af32 = RAWA && (flags[0] != 0);
    __syncthreads();

    int wave = tid >> 6, lane = tid & 63;
    int mrow = lane & 15, kq = lane >> 4;
    long row0 = (long)blockIdx.x * 64 + wave * 16;
    long row = row0 + mrow;
    bool valid = row < N;

    f32x4 acc[CT];
#pragma unroll
    for (int ct = 0; ct < CT; ct++) acc[ct] = (f32x4){0.f, 0.f, 0.f, 0.f};

    for (int kc = 0; kc < 4; kc++) {
        bf16x8 a = {0, 0, 0, 0, 0, 0, 0, 0};
        if (valid) {
            if (af32) {
                const float* ap = (const float*)A + row * 128 + kc * 32 + kq * 8;
                float4 f0 = *(const float4*)ap;
                float4 f1 = *(const float4*)(ap + 4);
                a[0] = (short)f2bf(f0.x); a[1] = (short)f2bf(f0.y);
                a[2] = (short)f2bf(f0.z); a[3] = (short)f2bf(f0.w);
                a[4] = (short)f2bf(f1.x); a[5] = (short)f2bf(f1.y);
                a[6] = (short)f2bf(f1.z); a[7] = (short)f2bf(f1.w);
            } else {
                a = *(const bf16x8*)((const unsigned short*)A + row * 128 + kc * 32 + kq * 8);
            }
        }
#pragma unroll
        for (int ct = 0; ct < CT; ct++) {
            bf16x8 b = *(const bf16x8*)(&wfrag[((kc * CT + ct) * 64 + lane) * 8]);
            acc[ct] = __builtin_amdgcn_mfma_f32_16x16x32_bf16(a, b, acc[ct], 0, 0, 0);
        }
    }

    float dv[4];
#pragma unroll
    for (int r = 0; r < 4; r++) {
        long orow = row0 + kq * 4 + r;
        dv[r] = (orow < N) ? dinv[orow] : 0.f;
    }
#pragma unroll
    for (int ct = 0; ct < CT; ct++) {
#pragma unroll
        for (int r = 0; r < 4; r++) {
            long orow = row0 + kq * 4 + r;
            if (orow < N) {
                float v = acc[ct][r] * dv[r];
                ht[orow * COLS + ct * 16 + mrow] = f2bf(v);
            }
        }
    }
}

// ---- layer-1 gather: wave/node, uint4 loads (4 rows per wave-load), fused bias+relu
// (R5 structure: VGPR ~20, no LDS, occupancy ~73% -- proven 62 us)
__global__ __launch_bounds__(256) void k_gather128(
    const unsigned short* __restrict__ h1t, const int* __restrict__ row_start,
    const int* __restrict__ deg_i, const float* __restrict__ dinv,
    const float* __restrict__ bb1, const int* __restrict__ adj,
    unsigned short* __restrict__ h1b, int N)
{
    int tid = threadIdx.x;
    int wave = tid >> 6, lane = tid & 63;
    int n = blockIdx.x * 4 + wave;
    if (n >= N) return;
    int g = lane >> 4, c = lane & 15;
    int cnt = deg_i[n];
    int start = row_start[n];
    int L = cnt + 1;                       // virtual list: neighbors + self at j==cnt

    float ac[8];
#pragma unroll
    for (int k = 0; k < 8; k++) ac[k] = 0.f;

    for (int jb = 0; jb < L; jb += 64) {
        int idx = jb + lane;
        int av = (idx < cnt) ? adj[start + idx] : n;
        int take = min(L - jb, 64);
        for (int jj = 0; jj < take; jj += 8) {
            int r0 = __shfl(av, jj + g);
            int r1 = __shfl(av, jj + 4 + g);
            bool m0 = (jj + g) < take;
            bool m1 = (jj + 4 + g) < take;
            uint4 v0 = make_uint4(0, 0, 0, 0), v1 = make_uint4(0, 0, 0, 0);
            if (m0) v0 = *(const uint4*)(h1t + (long)r0 * 128 + c * 8);
            if (m1) v1 = *(const uint4*)(h1t + (long)r1 * 128 + c * 8);
            acc8(ac, v0);
            acc8(ac, v1);
        }
    }
#pragma unroll
    for (int k = 0; k < 8; k++) {
        ac[k] += __shfl_xor(ac[k], 16);
        ac[k] += __shfl_xor(ac[k], 32);
    }
    if (g == 0) {
        float dv = dinv[n];
        float4 bA = *(const float4*)(bb1 + c * 8);
        float4 bB = *(const float4*)(bb1 + c * 8 + 4);
        float h0 = fmaxf(ac[0] * dv + bA.x, 0.f);
        float h1 = fmaxf(ac[1] * dv + bA.y, 0.f);
        float h2 = fmaxf(ac[2] * dv + bA.z, 0.f);
        float h3 = fmaxf(ac[3] * dv + bA.w, 0.f);
        float h4 = fmaxf(ac[4] * dv + bB.x, 0.f);
        float h5 = fmaxf(ac[5] * dv + bB.y, 0.f);
        float h6 = fmaxf(ac[6] * dv + bB.z, 0.f);
        float h7 = fmaxf(ac[7] * dv + bB.w, 0.f);
        uint4 pv;
        pv.x = (unsigned)f2bf(h0) | ((unsigned)f2bf(h1) << 16);
        pv.y = (unsigned)f2bf(h2) | ((unsigned)f2bf(h3) << 16);
        pv.z = (unsigned)f2bf(h4) | ((unsigned)f2bf(h5) << 16);
        pv.w = (unsigned)f2bf(h6) | ((unsigned)f2bf(h7) << 16);
        *(uint4*)(h1b + (long)n * 128 + c * 8) = pv;
    }
}

// ---- layer-2 gather + log_softmax: one node per LANE-PAIR (32 nodes/wave)
__global__ __launch_bounds__(256) void k_gather16(
    const unsigned short* __restrict__ h2t, const int* __restrict__ row_start,
    const int* __restrict__ deg_i, const float* __restrict__ dinv,
    const float* __restrict__ bb2, const int* __restrict__ adj,
    void* __restrict__ out, int N, const int* __restrict__ flags)
{
    int tid = threadIdx.x;
    int wave = tid >> 6, lane = tid & 63;
    int half = lane & 1;
    int n = (blockIdx.x * 4 + wave) * 32 + (lane >> 1);
    bool valid = n < N;
    int cnt = valid ? deg_i[n] : 0;
    int start = valid ? row_start[n] : 0;

    float ac[8];
#pragma unroll
    for (int k = 0; k < 8; k++) ac[k] = 0.f;

    int j = 0;
    for (; j + 2 <= cnt; j += 2) {
        int s0 = adj[start + j];
        int s1 = adj[start + j + 1];
        uint4 v0 = *(const uint4*)(h2t + (long)s0 * 16 + half * 8);
        uint4 v1 = *(const uint4*)(h2t + (long)s1 * 16 + half * 8);
        acc8(ac, v0);
        acc8(ac, v1);
    }
    if (j < cnt) {
        int s = adj[start + j];
        uint4 v = *(const uint4*)(h2t + (long)s * 16 + half * 8);
        acc8(ac, v);
    }
    if (!valid) return;
    {   // self-loop
        uint4 v = *(const uint4*)(h2t + (long)n * 16 + half * 8);
        acc8(ac, v);
    }
    float dv = dinv[n];
    float4 bA = *(const float4*)(bb2 + half * 8);
    float4 bB = *(const float4*)(bb2 + half * 8 + 4);
    float vv[8];
    vv[0] = ac[0] * dv + bA.x; vv[1] = ac[1] * dv + bA.y;
    vv[2] = ac[2] * dv + bA.z; vv[3] = ac[3] * dv + bA.w;
    vv[4] = ac[4] * dv + bB.x; vv[5] = ac[5] * dv + bB.y;
    vv[6] = ac[6] * dv + bB.z; vv[7] = ac[7] * dv + bB.w;
    float m8 = vv[0];
#pragma unroll
    for (int k = 1; k < 8; k++) m8 = fmaxf(m8, vv[k]);
    float m16 = fmaxf(m8, __shfl_xor(m8, 1));   // partner = other half of same node
    float s8 = 0.f;
#pragma unroll
    for (int k = 0; k < 8; k++) s8 += __expf(vv[k] - m16);
    float s16 = s8 + __shfl_xor(s8, 1);
    float lg = __logf(s16);
    if (flags[0]) {
        float* o = (float*)out + (long)n * 16 + half * 8;
        *(float4*)o = make_float4(vv[0] - m16 - lg, vv[1] - m16 - lg, vv[2] - m16 - lg, vv[3] - m16 - lg);
        *(float4*)(o + 4) = make_float4(vv[4] - m16 - lg, vv[5] - m16 - lg, vv[6] - m16 - lg, vv[7] - m16 - lg);
    } else {
        uint4 pv;
        pv.x = (unsigned)f2bf(vv[0] - m16 - lg) | ((unsigned)f2bf(vv[1] - m16 - lg) << 16);
        pv.y = (unsigned)f2bf(vv[2] - m16 - lg) | ((unsigned)f2bf(vv[3] - m16 - lg) << 16);
        pv.z = (unsigned)f2bf(vv[4] - m16 - lg) | ((unsigned)f2bf(vv[5] - m16 - lg) << 16);
        pv.w = (unsigned)f2bf(vv[6] - m16 - lg) | ((unsigned)f2bf(vv[7] - m16 - lg) << 16);
        *(uint4*)((unsigned short*)out + (long)n * 16 + half * 8) = pv;
    }
}

static inline size_t alignup(size_t x) { return (x + 255) & ~(size_t)255; }

extern "C" void kernel_launch(void* const* d_in, const int* in_sizes, int n_in,
                              void* d_out, int out_size, void* d_ws, size_t ws_size,
                              hipStream_t stream) {
    const void* xr  = d_in[0];
    const void* ei  = d_in[1];
    const void* W1r = d_in[2];
    const void* b1r = d_in[3];
    const void* W2r = d_in[4];
    const void* b2r = d_in[5];

    int N = in_sizes[0] / 128;
    int E = in_sizes[1] / 2;
    int NB = (N + 255) >> 8;

    char* w = (char*)d_ws;
    size_t off = 0;
    int*   flags = (int*)(w + off);   off += 256;      // flags[0..1]; gctr at flags[16]
    int*   gctr  = flags + 16;
    int*   deg_i = (int*)(w + off);   off = alignup(off + (size_t)N * 4);
    int*   row_start = (int*)(w + off); off = alignup(off + (size_t)N * 4);
    float* dinv  = (float*)(w + off); off = alignup(off + (size_t)N * 4);
    float* bb1   = (float*)(w + off); off = alignup(off + 128 * 4);
    float* bb2   = (float*)(w + off); off = alignup(off + 16 * 4);
    unsigned short* Wb1 = (unsigned short*)(w + off); off = alignup(off + 16384 * 2);
    unsigned short* Wb2 = (unsigned short*)(w + off); off = alignup(off + 2048 * 2);
    int*   bin_cnt = (int*)(w + off); off = alignup(off + (size_t)NB * 4);
    int*   adj   = (int*)(w + off);   off = alignup(off + (size_t)E * 4);
    unsigned short* h1t = (unsigned short*)(w + off); off = alignup(off + (size_t)N * 128 * 2);
    unsigned short* h1b = (unsigned short*)(w + off); off = alignup(off + (size_t)N * 128 * 2);
    unsigned short* h2t = (unsigned short*)(w + off); off = alignup(off + (size_t)N * 16 * 2);
    int* bin = (int*)h1b;   // overlay: bin (12.8 MB) dead before gather128 writes h1b

    int gG = (N + 63) / 64;
    int gA = (E + 4095) / 4096;
    int gW = (N + 3) / 4;
    int gP = (N + 127) / 128;   // gather16: 128 nodes per block (4 waves x 32)

    k_setup<<<75, 256, 0, stream>>>(W1r, W2r, b1r, b2r, (const unsigned int*)ei,
                                    Wb1, Wb2, bb1, bb2, bin_cnt, gctr, flags, NB);
    k_binA<<<gA, 256, 0, stream>>>(ei, bin_cnt, bin, E, NB, flags);
    k_binB<<<NB, 256, 0, stream>>>(bin_cnt, bin, deg_i, row_start, dinv, adj, gctr, N);

    k_gemm<8, true><<<gG, 256, 0, stream>>>(xr, Wb1, dinv, h1t, N, flags);
    k_gather128<<<gW, 256, 0, stream>>>(h1t, row_start, deg_i, dinv, bb1, adj, h1b, N);

    k_gemm<1, false><<<gG, 256, 0, stream>>>(h1b, Wb2, dinv, h2t, N, flags);
    k_gather16<<<gP, 256, 0, stream>>>(h2t, row_start, deg_i, dinv, bb2, adj, d_out, N, flags);
}

// Round 9
// 240.809 us; speedup vs baseline: 1.2543x; 1.0213x over previous
//
#include <hip/hip_runtime.h>
#include <hip/hip_bf16.h>

typedef short bf16x8 __attribute__((ext_vector_type(8)));
typedef float f32x4 __attribute__((ext_vector_type(4)));

#define BCAP 8192   // per-bucket bin capacity (mean ~4096 for E=1.6M, NB=391)

__device__ inline float bf2f(unsigned short u) {
    union { unsigned int i; float f; } v; v.i = ((unsigned int)u) << 16; return v.f;
}
__device__ inline unsigned short f2bf(float f) {
    union { float f; unsigned int i; } v; v.f = f;
    unsigned int r = v.i + 0x7FFFu + ((v.i >> 16) & 1u);
    return (unsigned short)(r >> 16);
}
__device__ inline float u_lo(unsigned u) {
    union { unsigned i; float f; } v; v.i = u << 16; return v.f;
}
__device__ inline float u_hi(unsigned u) {
    union { unsigned i; float f; } v; v.i = u & 0xFFFF0000u; return v.f;
}
__device__ inline void acc8(float* ac, uint4 v) {
    ac[0] += u_lo(v.x); ac[1] += u_hi(v.x);
    ac[2] += u_lo(v.y); ac[3] += u_hi(v.y);
    ac[4] += u_lo(v.z); ac[5] += u_hi(v.z);
    ac[6] += u_lo(v.w); ac[7] += u_hi(v.w);
}

// ---- fused setup: weight/bias conversion + bin_cnt/gctr init + flags ----
__global__ __launch_bounds__(256) void k_setup(
    const void* __restrict__ W1r, const void* __restrict__ W2r,
    const void* __restrict__ b1r, const void* __restrict__ b2r,
    const unsigned int* __restrict__ eiraw,
    unsigned short* __restrict__ Wb1, unsigned short* __restrict__ Wb2,
    float* __restrict__ bb1, float* __restrict__ bb2,
    int* __restrict__ bin_cnt, int* gctr, int* flags, int NB)
{
    __shared__ int cs, ce;
    int blk = blockIdx.x, tid = threadIdx.x;
    const unsigned short* w1u = (const unsigned short*)W1r;
    int lf = 0;
    for (int i = tid; i < 4096; i += 256) {
        unsigned e = (w1u[i] >> 7) & 0xFF;
        lf += (e >= 0x90);               // |val| >= 2^17: impossible for real bf16 weights
    }
    for (int o = 32; o; o >>= 1) lf += __shfl_down(lf, o);
    if (tid == 0) { cs = 0; ce = 0; }
    __syncthreads();
    if ((tid & 63) == 0 && lf) atomicAdd(&cs, lf);
    __syncthreads();
    bool isf32 = cs > 16;

    if (blk < 64) {
        int i = blk * 256 + tid;
        Wb1[i] = isf32 ? f2bf(((const float*)W1r)[i]) : ((const unsigned short*)W1r)[i];
    } else if (blk < 72) {
        int i = (blk - 64) * 256 + tid;
        Wb2[i] = isf32 ? f2bf(((const float*)W2r)[i]) : ((const unsigned short*)W2r)[i];
    } else if (blk == 72) {
        if (tid < 128) bb1[tid] = isf32 ? ((const float*)b1r)[tid] : bf2f(((const unsigned short*)b1r)[tid]);
        else if (tid < 144) bb2[tid - 128] = isf32 ? ((const float*)b2r)[tid - 128] : bf2f(((const unsigned short*)b2r)[tid - 128]);
    } else if (blk == 73) {
        for (int i = tid; i < NB; i += 256) bin_cnt[i] = 0;
        if (tid == 0) *gctr = 0;
    } else {                             // blk == 74: flags
        int le = 0;
        for (int i = tid; i < 128; i += 256)
            if ((i & 1) && eiraw[i] != 0) le++;
        for (int o = 32; o; o >>= 1) le += __shfl_down(le, o);
        if ((tid & 63) == 0 && le) atomicAdd(&ce, le);
        __syncthreads();
        if (tid == 0) { flags[0] = isf32 ? 1 : 0; flags[1] = (ce == 0) ? 1 : 0; }
    }
}

// ---- phase A: LDS bucket-sort 4096 edges, then COALESCED run-writes into bin ----
// bin layout unchanged: bucket-major regions, packed (ldst<<20)|src
__global__ __launch_bounds__(256) void k_binA(const void* __restrict__ ei,
                                              int* __restrict__ bin_cnt, int* __restrict__ bin,
                                              int E, int NB, const int* __restrict__ flags) {
    __shared__ int cnt[512];
    __shared__ int pfx[512];
    __shared__ int cur[512];
    __shared__ int dl[512];
    __shared__ int ssum[256];
    __shared__ int sortw[4096];
    __shared__ unsigned short sortb[4096];
    int tid = threadIdx.x;
    for (int i = tid; i < 512; i += 256) cnt[i] = 0;
    bool i64 = flags[1] != 0;
    long e0 = (long)blockIdx.x * 4096;
    int total = (int)min((long)4096, (long)E - e0);
    int src[16], dst[16];
#pragma unroll
    for (int i = 0; i < 16; i++) {
        long e = e0 + i * 256 + tid;
        if (e < E) {
            if (i64) {
                src[i] = (int)((const long long*)ei)[e];
                dst[i] = (int)((const long long*)ei)[(long)E + e];
            } else {
                src[i] = ((const int*)ei)[e];
                dst[i] = ((const int*)ei)[(long)E + e];
            }
        } else dst[i] = -1;
    }
    __syncthreads();
#pragma unroll
    for (int i = 0; i < 16; i++)
        if (dst[i] >= 0) atomicAdd(&cnt[dst[i] >> 8], 1);
    __syncthreads();
    // 512-wide exclusive prefix via 256-thread Hillis-Steele (2 buckets/thread)
    int c0 = cnt[2 * tid], c1 = cnt[2 * tid + 1];
    int v = c0 + c1;
    ssum[tid] = v;
    __syncthreads();
    int val = v;
    for (int off = 1; off < 256; off <<= 1) {
        int t = (tid >= off) ? ssum[tid - off] : 0;
        __syncthreads();
        val += t;
        ssum[tid] = val;
        __syncthreads();
    }
    int excl = val - v;
    pfx[2 * tid] = excl;
    pfx[2 * tid + 1] = excl + c0;
    cur[2 * tid] = excl;
    cur[2 * tid + 1] = excl + c0;
    __syncthreads();
    // place into LDS-sorted buffer
#pragma unroll
    for (int i = 0; i < 16; i++) {
        int d = dst[i];
        if (d >= 0) {
            int b = d >> 8;
            int p = atomicAdd(&cur[b], 1);
            sortw[p] = ((d & 255) << 20) | src[i];
            sortb[p] = (unsigned short)b;
        }
    }
    // reserve global runs per bucket
    for (int b = tid; b < 512; b += 256) {
        int c = (b < NB) ? cnt[b] : 0;
        int base = c ? atomicAdd(&bin_cnt[b], c) : 0;
        dl[b] = base - pfx[b];
    }
    __syncthreads();
    // coalesced run write-out
    for (int i = tid; i < total; i += 256) {
        int b = sortb[i];
        int pib = dl[b] + i;                 // = base + (i - pfx[b]) : position in bucket
        if (pib < BCAP) bin[(long)b * BCAP + pib] = sortw[i];
    }
}

// ---- phase B: per-bucket CSR build in LDS; adj staged in LDS, coalesced write ----
__global__ __launch_bounds__(256) void k_binB(const int* __restrict__ bin_cnt,
                                              const int* __restrict__ bin,
                                              int* __restrict__ deg_i, int* __restrict__ row_start,
                                              float* __restrict__ dinv, int* __restrict__ adj,
                                              int* gctr, int N) {
    __shared__ int deg[256];
    __shared__ int sm[256];
    __shared__ int cur[256];
    __shared__ int sadj[BCAP];
    __shared__ int sbase;
    int b = blockIdx.x, tid = threadIdx.x;
    int cnt = min(bin_cnt[b], BCAP);
    const int* bp = bin + (long)b * BCAP;
    deg[tid] = 0;
    __syncthreads();
    for (int i = tid; i < cnt; i += 256)
        atomicAdd(&deg[bp[i] >> 20], 1);
    __syncthreads();
    int d = deg[tid];
    int val = d;
    sm[tid] = val;
    __syncthreads();
    for (int off = 1; off < 256; off <<= 1) {
        int t = (tid >= off) ? sm[tid - off] : 0;
        __syncthreads();
        val += t;
        sm[tid] = val;
        __syncthreads();
    }
    if (tid == 255) sbase = atomicAdd(gctr, val);
    __syncthreads();
    int lstart = val - d;                    // local start within bucket slice
    cur[tid] = lstart;
    int n = (b << 8) + tid;
    if (n < N) {
        deg_i[n] = d;
        row_start[n] = sbase + lstart;
        dinv[n] = rsqrtf((float)(d + 1));
    }
    __syncthreads();
    // place into LDS (random LDS writes, cheap), then linear coalesced global write
    for (int i = tid; i < cnt; i += 256) {
        int w = bp[i];
        int pos = atomicAdd(&cur[w >> 20], 1);
        sadj[pos] = w & 0xFFFFF;
    }
    __syncthreads();
    for (int i = tid; i < cnt; i += 256)
        adj[sbase + i] = sadj[i];
}

// ---- MFMA GEMM: A[N,128] @ Wb[128,CT*16] -> h~ = (A@W)*dinv[row], bf16
template <int CT, bool RAWA>
__global__ __launch_bounds__(256) void k_gemm(
    const void* __restrict__ A, const unsigned short* __restrict__ Wb,
    const float* __restrict__ dinv, unsigned short* __restrict__ ht, int N,
    const int* __restrict__ flags)
{
    constexpr int COLS = CT * 16;
    __shared__ unsigned short wfrag[4 * CT * 64 * 8];
    int tid = threadIdx.x;
    for (int idx = tid; idx < 4 * CT * 64; idx += 256) {
        int kc = idx / (CT * 64);
        int rem = idx % (CT * 64);
        int ct = rem / 64, l = rem % 64;
        int n = ct * 16 + (l & 15);
        int kbase = kc * 32 + (l >> 4) * 8;
        unsigned short* d = &wfrag[idx * 8];
#pragma unroll
        for (int j = 0; j < 8; j++) d[j] = Wb[(kbase + j) * COLS + n];
    }
    bool af32 = RAWA && (flags[0] != 0);
    __syncthreads();

    int wave = tid >> 6, lane = tid & 63;
    int mrow = lane & 15, kq = lane >> 4;
    long row0 = (long)blockIdx.x * 64 + wave * 16;
    long row = row0 + mrow;
    bool valid = row < N;

    f32x4 acc[CT];
#pragma unroll
    for (int ct = 0; ct < CT; ct++) acc[ct] = (f32x4){0.f, 0.f, 0.f, 0.f};

    for (int kc = 0; kc < 4; kc++) {
        bf16x8 a = {0, 0, 0, 0, 0, 0, 0, 0};
        if (valid) {
            if (af32) {
                const float* ap = (const float*)A + row * 128 + kc * 32 + kq * 8;
                float4 f0 = *(const float4*)ap;
                float4 f1 = *(const float4*)(ap + 4);
                a[0] = (short)f2bf(f0.x); a[1] = (short)f2bf(f0.y);
                a[2] = (short)f2bf(f0.z); a[3] = (short)f2bf(f0.w);
                a[4] = (short)f2bf(f1.x); a[5] = (short)f2bf(f1.y);
                a[6] = (short)f2bf(f1.z); a[7] = (short)f2bf(f1.w);
            } else {
                a = *(const bf16x8*)((const unsigned short*)A + row * 128 + kc * 32 + kq * 8);
            }
        }
#pragma unroll
        for (int ct = 0; ct < CT; ct++) {
            bf16x8 b = *(const bf16x8*)(&wfrag[((kc * CT + ct) * 64 + lane) * 8]);
            acc[ct] = __builtin_amdgcn_mfma_f32_16x16x32_bf16(a, b, acc[ct], 0, 0, 0);
        }
    }

    float dv[4];
#pragma unroll
    for (int r = 0; r < 4; r++) {
        long orow = row0 + kq * 4 + r;
        dv[r] = (orow < N) ? dinv[orow] : 0.f;
    }
#pragma unroll
    for (int ct = 0; ct < CT; ct++) {
#pragma unroll
        for (int r = 0; r < 4; r++) {
            long orow = row0 + kq * 4 + r;
            if (orow < N) {
                float v = acc[ct][r] * dv[r];
                ht[orow * COLS + ct * 16 + mrow] = f2bf(v);
            }
        }
    }
}

// ---- layer-1 gather: wave/node, uint4 loads (4 rows per wave-load), fused bias+relu
__global__ __launch_bounds__(256) void k_gather128(
    const unsigned short* __restrict__ h1t, const int* __restrict__ row_start,
    const int* __restrict__ deg_i, const float* __restrict__ dinv,
    const float* __restrict__ bb1, const int* __restrict__ adj,
    unsigned short* __restrict__ h1b, int N)
{
    int tid = threadIdx.x;
    int wave = tid >> 6, lane = tid & 63;
    int n = blockIdx.x * 4 + wave;
    if (n >= N) return;
    int g = lane >> 4, c = lane & 15;
    int cnt = deg_i[n];
    int start = row_start[n];
    int L = cnt + 1;                       // virtual list: neighbors + self at j==cnt

    float ac[8];
#pragma unroll
    for (int k = 0; k < 8; k++) ac[k] = 0.f;

    for (int jb = 0; jb < L; jb += 64) {
        int idx = jb + lane;
        int av = (idx < cnt) ? adj[start + idx] : n;
        int take = min(L - jb, 64);
        for (int jj = 0; jj < take; jj += 8) {
            int r0 = __shfl(av, jj + g);
            int r1 = __shfl(av, jj + 4 + g);
            bool m0 = (jj + g) < take;
            bool m1 = (jj + 4 + g) < take;
            uint4 v0 = make_uint4(0, 0, 0, 0), v1 = make_uint4(0, 0, 0, 0);
            if (m0) v0 = *(const uint4*)(h1t + (long)r0 * 128 + c * 8);
            if (m1) v1 = *(const uint4*)(h1t + (long)r1 * 128 + c * 8);
            acc8(ac, v0);
            acc8(ac, v1);
        }
    }
#pragma unroll
    for (int k = 0; k < 8; k++) {
        ac[k] += __shfl_xor(ac[k], 16);
        ac[k] += __shfl_xor(ac[k], 32);
    }
    if (g == 0) {
        float dv = dinv[n];
        float4 bA = *(const float4*)(bb1 + c * 8);
        float4 bB = *(const float4*)(bb1 + c * 8 + 4);
        float h0 = fmaxf(ac[0] * dv + bA.x, 0.f);
        float h1 = fmaxf(ac[1] * dv + bA.y, 0.f);
        float h2 = fmaxf(ac[2] * dv + bA.z, 0.f);
        float h3 = fmaxf(ac[3] * dv + bA.w, 0.f);
        float h4 = fmaxf(ac[4] * dv + bB.x, 0.f);
        float h5 = fmaxf(ac[5] * dv + bB.y, 0.f);
        float h6 = fmaxf(ac[6] * dv + bB.z, 0.f);
        float h7 = fmaxf(ac[7] * dv + bB.w, 0.f);
        uint4 pv;
        pv.x = (unsigned)f2bf(h0) | ((unsigned)f2bf(h1) << 16);
        pv.y = (unsigned)f2bf(h2) | ((unsigned)f2bf(h3) << 16);
        pv.z = (unsigned)f2bf(h4) | ((unsigned)f2bf(h5) << 16);
        pv.w = (unsigned)f2bf(h6) | ((unsigned)f2bf(h7) << 16);
        *(uint4*)(h1b + (long)n * 128 + c * 8) = pv;
    }
}

// ---- layer-2 gather + log_softmax: one node per LANE-PAIR (32 nodes/wave)
__global__ __launch_bounds__(256) void k_gather16(
    const unsigned short* __restrict__ h2t, const int* __restrict__ row_start,
    const int* __restrict__ deg_i, const float* __restrict__ dinv,
    const float* __restrict__ bb2, const int* __restrict__ adj,
    void* __restrict__ out, int N, const int* __restrict__ flags)
{
    int tid = threadIdx.x;
    int wave = tid >> 6, lane = tid & 63;
    int half = lane & 1;
    int n = (blockIdx.x * 4 + wave) * 32 + (lane >> 1);
    bool valid = n < N;
    int cnt = valid ? deg_i[n] : 0;
    int start = valid ? row_start[n] : 0;

    float ac[8];
#pragma unroll
    for (int k = 0; k < 8; k++) ac[k] = 0.f;

    int j = 0;
    for (; j + 2 <= cnt; j += 2) {
        int s0 = adj[start + j];
        int s1 = adj[start + j + 1];
        uint4 v0 = *(const uint4*)(h2t + (long)s0 * 16 + half * 8);
        uint4 v1 = *(const uint4*)(h2t + (long)s1 * 16 + half * 8);
        acc8(ac, v0);
        acc8(ac, v1);
    }
    if (j < cnt) {
        int s = adj[start + j];
        uint4 v = *(const uint4*)(h2t + (long)s * 16 + half * 8);
        acc8(ac, v);
    }
    if (!valid) return;
    {   // self-loop
        uint4 v = *(const uint4*)(h2t + (long)n * 16 + half * 8);
        acc8(ac, v);
    }
    float dv = dinv[n];
    float4 bA = *(const float4*)(bb2 + half * 8);
    float4 bB = *(const float4*)(bb2 + half * 8 + 4);
    float vv[8];
    vv[0] = ac[0] * dv + bA.x; vv[1] = ac[1] * dv + bA.y;
    vv[2] = ac[2] * dv + bA.z; vv[3] = ac[3] * dv + bA.w;
    vv[4] = ac[4] * dv + bB.x; vv[5] = ac[5] * dv + bB.y;
    vv[6] = ac[6] * dv + bB.z; vv[7] = ac[7] * dv + bB.w;
    float m8 = vv[0];
#pragma unroll
    for (int k = 1; k < 8; k++) m8 = fmaxf(m8, vv[k]);
    float m16 = fmaxf(m8, __shfl_xor(m8, 1));   // partner = other half of same node
    float s8 = 0.f;
#pragma unroll
    for (int k = 0; k < 8; k++) s8 += __expf(vv[k] - m16);
    float s16 = s8 + __shfl_xor(s8, 1);
    float lg = __logf(s16);
    if (flags[0]) {
        float* o = (float*)out + (long)n * 16 + half * 8;
        *(float4*)o = make_float4(vv[0] - m16 - lg, vv[1] - m16 - lg, vv[2] - m16 - lg, vv[3] - m16 - lg);
        *(float4*)(o + 4) = make_float4(vv[4] - m16 - lg, vv[5] - m16 - lg, vv[6] - m16 - lg, vv[7] - m16 - lg);
    } else {
        uint4 pv;
        pv.x = (unsigned)f2bf(vv[0] - m16 - lg) | ((unsigned)f2bf(vv[1] - m16 - lg) << 16);
        pv.y = (unsigned)f2bf(vv[2] - m16 - lg) | ((unsigned)f2bf(vv[3] - m16 - lg) << 16);
        pv.z = (unsigned)f2bf(vv[4] - m16 - lg) | ((unsigned)f2bf(vv[5] - m16 - lg) << 16);
        pv.w = (unsigned)f2bf(vv[6] - m16 - lg) | ((unsigned)f2bf(vv[7] - m16 - lg) << 16);
        *(uint4*)((unsigned short*)out + (long)n * 16 + half * 8) = pv;
    }
}

static inline size_t alignup(size_t x) { return (x + 255) & ~(size_t)255; }

extern "C" void kernel_launch(void* const* d_in, const int* in_sizes, int n_in,
                              void* d_out, int out_size, void* d_ws, size_t ws_size,
                              hipStream_t stream) {
    const void* xr  = d_in[0];
    const void* ei  = d_in[1];
    const void* W1r = d_in[2];
    const void* b1r = d_in[3];
    const void* W2r = d_in[4];
    const void* b2r = d_in[5];

    int N = in_sizes[0] / 128;
    int E = in_sizes[1] / 2;
    int NB = (N + 255) >> 8;

    char* w = (char*)d_ws;
    size_t off = 0;
    int*   flags = (int*)(w + off);   off += 256;      // flags[0..1]; gctr at flags[16]
    int*   gctr  = flags + 16;
    int*   deg_i = (int*)(w + off);   off = alignup(off + (size_t)N * 4);
    int*   row_start = (int*)(w + off); off = alignup(off + (size_t)N * 4);
    float* dinv  = (float*)(w + off); off = alignup(off + (size_t)N * 4);
    float* bb1   = (float*)(w + off); off = alignup(off + 128 * 4);
    float* bb2   = (float*)(w + off); off = alignup(off + 16 * 4);
    unsigned short* Wb1 = (unsigned short*)(w + off); off = alignup(off + 16384 * 2);
    unsigned short* Wb2 = (unsigned short*)(w + off); off = alignup(off + 2048 * 2);
    int*   bin_cnt = (int*)(w + off); off = alignup(off + (size_t)NB * 4);
    int*   adj   = (int*)(w + off);   off = alignup(off + (size_t)E * 4);
    unsigned short* h1t = (unsigned short*)(w + off); off = alignup(off + (size_t)N * 128 * 2);
    unsigned short* h1b = (unsigned short*)(w + off); off = alignup(off + (size_t)N * 128 * 2);
    unsigned short* h2t = (unsigned short*)(w + off); off = alignup(off + (size_t)N * 16 * 2);
    int* bin = (int*)h1b;   // overlay: bin (12.8 MB) dead before gather128 writes h1b

    int gG = (N + 63) / 64;
    int gA = (E + 4095) / 4096;
    int gW = (N + 3) / 4;
    int gP = (N + 127) / 128;   // gather16: 128 nodes per block (4 waves x 32)

    k_setup<<<75, 256, 0, stream>>>(W1r, W2r, b1r, b2r, (const unsigned int*)ei,
                                    Wb1, Wb2, bb1, bb2, bin_cnt, gctr, flags, NB);
    k_binA<<<gA, 256, 0, stream>>>(ei, bin_cnt, bin, E, NB, flags);
    k_binB<<<NB, 256, 0, stream>>>(bin_cnt, bin, deg_i, row_start, dinv, adj, gctr, N);

    k_gemm<8, true><<<gG, 256, 0, stream>>>(xr, Wb1, dinv, h1t, N, flags);
    k_gather128<<<gW, 256, 0, stream>>>(h1t, row_start, deg_i, dinv, bb1, adj, h1b, N);

    k_gemm<1, false><<<gG, 256, 0, stream>>>(h1b, Wb2, dinv, h2t, N, flags);
    k_gather16<<<gP, 256, 0, stream>>>(h2t, row_start, deg_i, dinv, bb2, adj, d_out, N, flags);
}

// Round 10
// 232.974 us; speedup vs baseline: 1.2964x; 1.0336x over previous
//
#include <hip/hip_runtime.h>
#include <hip/hip_bf16.h>

typedef short bf16x8 __attribute__((ext_vector_type(8)));
typedef float f32x4 __attribute__((ext_vector_type(4)));

#define BCAP 8192   // per-bucket bin capacity (mean ~4096 for E=1.6M, NB=391)

__device__ inline float bf2f(unsigned short u) {
    union { unsigned int i; float f; } v; v.i = ((unsigned int)u) << 16; return v.f;
}
__device__ inline unsigned short f2bf(float f) {
    union { float f; unsigned int i; } v; v.f = f;
    unsigned int r = v.i + 0x7FFFu + ((v.i >> 16) & 1u);
    return (unsigned short)(r >> 16);
}
__device__ inline float u_lo(unsigned u) {
    union { unsigned i; float f; } v; v.i = u << 16; return v.f;
}
__device__ inline float u_hi(unsigned u) {
    union { unsigned i; float f; } v; v.i = u & 0xFFFF0000u; return v.f;
}
__device__ inline void acc8(float* ac, uint4 v) {
    ac[0] += u_lo(v.x); ac[1] += u_hi(v.x);
    ac[2] += u_lo(v.y); ac[3] += u_hi(v.y);
    ac[4] += u_lo(v.z); ac[5] += u_hi(v.z);
    ac[6] += u_lo(v.w); ac[7] += u_hi(v.w);
}
__device__ inline void acc8s(float* ac, uint4 v, float d) {   // fma form: ac += d*v
    ac[0] += d * u_lo(v.x); ac[1] += d * u_hi(v.x);
    ac[2] += d * u_lo(v.y); ac[3] += d * u_hi(v.y);
    ac[4] += d * u_lo(v.z); ac[5] += d * u_hi(v.z);
    ac[6] += d * u_lo(v.w); ac[7] += d * u_hi(v.w);
}

// ---- fused setup: weight/bias conversion + bin_cnt/gctr init + flags ----
__global__ __launch_bounds__(256) void k_setup(
    const void* __restrict__ W1r, const void* __restrict__ W2r,
    const void* __restrict__ b1r, const void* __restrict__ b2r,
    const unsigned int* __restrict__ eiraw,
    unsigned short* __restrict__ Wb1, unsigned short* __restrict__ Wb2,
    float* __restrict__ bb1, float* __restrict__ bb2,
    int* __restrict__ bin_cnt, int* gctr, int* flags, int NB)
{
    __shared__ int cs, ce;
    int blk = blockIdx.x, tid = threadIdx.x;
    const unsigned short* w1u = (const unsigned short*)W1r;
    int lf = 0;
    for (int i = tid; i < 4096; i += 256) {
        unsigned e = (w1u[i] >> 7) & 0xFF;
        lf += (e >= 0x90);               // |val| >= 2^17: impossible for real bf16 weights
    }
    for (int o = 32; o; o >>= 1) lf += __shfl_down(lf, o);
    if (tid == 0) { cs = 0; ce = 0; }
    __syncthreads();
    if ((tid & 63) == 0 && lf) atomicAdd(&cs, lf);
    __syncthreads();
    bool isf32 = cs > 16;

    if (blk < 64) {
        int i = blk * 256 + tid;
        Wb1[i] = isf32 ? f2bf(((const float*)W1r)[i]) : ((const unsigned short*)W1r)[i];
    } else if (blk < 72) {
        int i = (blk - 64) * 256 + tid;
        Wb2[i] = isf32 ? f2bf(((const float*)W2r)[i]) : ((const unsigned short*)W2r)[i];
    } else if (blk == 72) {
        if (tid < 128) bb1[tid] = isf32 ? ((const float*)b1r)[tid] : bf2f(((const unsigned short*)b1r)[tid]);
        else if (tid < 144) bb2[tid - 128] = isf32 ? ((const float*)b2r)[tid - 128] : bf2f(((const unsigned short*)b2r)[tid - 128]);
    } else if (blk == 73) {
        for (int i = tid; i < NB; i += 256) bin_cnt[i] = 0;
        if (tid == 0) *gctr = 0;
    } else {                             // blk == 74: flags
        int le = 0;
        for (int i = tid; i < 128; i += 256)
            if ((i & 1) && eiraw[i] != 0) le++;
        for (int o = 32; o; o >>= 1) le += __shfl_down(le, o);
        if ((tid & 63) == 0 && le) atomicAdd(&ce, le);
        __syncthreads();
        if (tid == 0) { flags[0] = isf32 ? 1 : 0; flags[1] = (ce == 0) ? 1 : 0; }
    }
}

// ---- binA body: LDS bucket-sort 4096 edges, coalesced run-writes into bin ----
__device__ __forceinline__ void binA_body(int* smem, const void* __restrict__ ei,
                                          int* __restrict__ bin_cnt, int* __restrict__ bin,
                                          int E, int NB, const int* __restrict__ flags) {
    int* cnt  = smem;                     // 512
    int* pfx  = smem + 512;               // 512
    int* cur  = smem + 1024;              // 512
    int* dl   = smem + 1536;              // 512
    int* ssum = smem + 2048;              // 256
    int* sortw = smem + 2304;             // 4096
    unsigned short* sortb = (unsigned short*)(smem + 6400);   // 4096 shorts
    int tid = threadIdx.x;
    for (int i = tid; i < 512; i += 256) cnt[i] = 0;
    bool i64 = flags[1] != 0;
    long e0 = (long)blockIdx.x * 4096;
    int total = (int)min((long)4096, (long)E - e0);
    int src[16], dst[16];
#pragma unroll
    for (int i = 0; i < 16; i++) {
        long e = e0 + i * 256 + tid;
        if (e < E) {
            if (i64) {
                src[i] = (int)((const long long*)ei)[e];
                dst[i] = (int)((const long long*)ei)[(long)E + e];
            } else {
                src[i] = ((const int*)ei)[e];
                dst[i] = ((const int*)ei)[(long)E + e];
            }
        } else dst[i] = -1;
    }
    __syncthreads();
#pragma unroll
    for (int i = 0; i < 16; i++)
        if (dst[i] >= 0) atomicAdd(&cnt[dst[i] >> 8], 1);
    __syncthreads();
    int c0 = cnt[2 * tid], c1 = cnt[2 * tid + 1];
    int v = c0 + c1;
    ssum[tid] = v;
    __syncthreads();
    int val = v;
    for (int off = 1; off < 256; off <<= 1) {
        int t = (tid >= off) ? ssum[tid - off] : 0;
        __syncthreads();
        val += t;
        ssum[tid] = val;
        __syncthreads();
    }
    int excl = val - v;
    pfx[2 * tid] = excl;
    pfx[2 * tid + 1] = excl + c0;
    cur[2 * tid] = excl;
    cur[2 * tid + 1] = excl + c0;
    __syncthreads();
#pragma unroll
    for (int i = 0; i < 16; i++) {
        int d = dst[i];
        if (d >= 0) {
            int b = d >> 8;
            int p = atomicAdd(&cur[b], 1);
            sortw[p] = ((d & 255) << 20) | src[i];
            sortb[p] = (unsigned short)b;
        }
    }
    for (int b = tid; b < 512; b += 256) {
        int c = (b < NB) ? cnt[b] : 0;
        int base = c ? atomicAdd(&bin_cnt[b], c) : 0;
        dl[b] = base - pfx[b];
    }
    __syncthreads();
    for (int i = tid; i < total; i += 256) {
        int b = sortb[i];
        int pib = dl[b] + i;
        if (pib < BCAP) bin[(long)b * BCAP + pib] = sortw[i];
    }
}

// ---- gemm1 body: X[N,128] @ Wb1[128,128] -> h1t (bf16, UNSCALED) ----
__device__ __forceinline__ void gemm1_body(unsigned short* wfrag, const void* __restrict__ A,
                                           const unsigned short* __restrict__ Wb,
                                           unsigned short* __restrict__ ht, int N,
                                           const int* __restrict__ flags, int bid) {
    int tid = threadIdx.x;
    for (int idx = tid; idx < 4 * 8 * 64; idx += 256) {
        int kc = idx / (8 * 64);
        int rem = idx % (8 * 64);
        int ct = rem / 64, l = rem % 64;
        int n = ct * 16 + (l & 15);
        int kbase = kc * 32 + (l >> 4) * 8;
        unsigned short* d = &wfrag[idx * 8];
#pragma unroll
        for (int j = 0; j < 8; j++) d[j] = Wb[(kbase + j) * 128 + n];
    }
    bool af32 = flags[0] != 0;
    __syncthreads();

    int wave = tid >> 6, lane = tid & 63;
    int mrow = lane & 15, kq = lane >> 4;
    long row0 = (long)bid * 64 + wave * 16;
    long row = row0 + mrow;
    bool valid = row < N;

    f32x4 acc[8];
#pragma unroll
    for (int ct = 0; ct < 8; ct++) acc[ct] = (f32x4){0.f, 0.f, 0.f, 0.f};

    for (int kc = 0; kc < 4; kc++) {
        bf16x8 a = {0, 0, 0, 0, 0, 0, 0, 0};
        if (valid) {
            if (af32) {
                const float* ap = (const float*)A + row * 128 + kc * 32 + kq * 8;
                float4 f0 = *(const float4*)ap;
                float4 f1 = *(const float4*)(ap + 4);
                a[0] = (short)f2bf(f0.x); a[1] = (short)f2bf(f0.y);
                a[2] = (short)f2bf(f0.z); a[3] = (short)f2bf(f0.w);
                a[4] = (short)f2bf(f1.x); a[5] = (short)f2bf(f1.y);
                a[6] = (short)f2bf(f1.z); a[7] = (short)f2bf(f1.w);
            } else {
                a = *(const bf16x8*)((const unsigned short*)A + row * 128 + kc * 32 + kq * 8);
            }
        }
#pragma unroll
        for (int ct = 0; ct < 8; ct++) {
            bf16x8 b = *(const bf16x8*)(&wfrag[((kc * 8 + ct) * 64 + lane) * 8]);
            acc[ct] = __builtin_amdgcn_mfma_f32_16x16x32_bf16(a, b, acc[ct], 0, 0, 0);
        }
    }
#pragma unroll
    for (int ct = 0; ct < 8; ct++) {
#pragma unroll
        for (int r = 0; r < 4; r++) {
            long orow = row0 + kq * 4 + r;
            if (orow < N) ht[orow * 128 + ct * 16 + mrow] = f2bf(acc[ct][r]);
        }
    }
}

// ---- fat dispatch: blocks [0,gA) = binA, [gA,gA+gG) = gemm1 (independent work) ----
__global__ __launch_bounds__(256) void k_front(
    const void* __restrict__ ei, int* __restrict__ bin_cnt, int* __restrict__ bin,
    int E, int NB, const int* __restrict__ flags,
    const void* __restrict__ xr, const unsigned short* __restrict__ Wb1,
    unsigned short* __restrict__ h1t, int N, int gA)
{
    __shared__ __align__(16) int smem[8448];   // 33,792 B arena (binA layout / gemm wfrag)
    if ((int)blockIdx.x < gA)
        binA_body(smem, ei, bin_cnt, bin, E, NB, flags);
    else
        gemm1_body((unsigned short*)smem, xr, Wb1, h1t, N, flags, (int)blockIdx.x - gA);
}

// ---- phase B: per-bucket CSR build in LDS; adj staged in LDS, coalesced write ----
__global__ __launch_bounds__(256) void k_binB(const int* __restrict__ bin_cnt,
                                              const int* __restrict__ bin,
                                              int* __restrict__ deg_i, int* __restrict__ row_start,
                                              float* __restrict__ dinv, int* __restrict__ adj,
                                              int* gctr, int N) {
    __shared__ int deg[256];
    __shared__ int sm[256];
    __shared__ int cur[256];
    __shared__ int sadj[BCAP];
    __shared__ int sbase;
    int b = blockIdx.x, tid = threadIdx.x;
    int cnt = min(bin_cnt[b], BCAP);
    const int* bp = bin + (long)b * BCAP;
    deg[tid] = 0;
    __syncthreads();
    for (int i = tid; i < cnt; i += 256)
        atomicAdd(&deg[bp[i] >> 20], 1);
    __syncthreads();
    int d = deg[tid];
    int val = d;
    sm[tid] = val;
    __syncthreads();
    for (int off = 1; off < 256; off <<= 1) {
        int t = (tid >= off) ? sm[tid - off] : 0;
        __syncthreads();
        val += t;
        sm[tid] = val;
        __syncthreads();
    }
    if (tid == 255) sbase = atomicAdd(gctr, val);
    __syncthreads();
    int lstart = val - d;
    cur[tid] = lstart;
    int n = (b << 8) + tid;
    if (n < N) {
        deg_i[n] = d;
        row_start[n] = sbase + lstart;
        dinv[n] = rsqrtf((float)(d + 1));
    }
    __syncthreads();
    for (int i = tid; i < cnt; i += 256) {
        int w = bp[i];
        int pos = atomicAdd(&cur[w >> 20], 1);
        sadj[pos] = w & 0xFFFFF;
    }
    __syncthreads();
    for (int i = tid; i < cnt; i += 256)
        adj[sbase + i] = sadj[i];
}

// ---- standalone MFMA GEMM (layer 2): h1b[N,128] @ Wb2[128,16] -> h2t*dinv, bf16
__global__ __launch_bounds__(256) void k_gemm2(
    const unsigned short* __restrict__ A, const unsigned short* __restrict__ Wb,
    const float* __restrict__ dinv, unsigned short* __restrict__ ht, int N)
{
    __shared__ unsigned short wfrag[4 * 64 * 8];
    int tid = threadIdx.x;
    for (int idx = tid; idx < 4 * 64; idx += 256) {
        int kc = idx / 64, l = idx % 64;
        int n = l & 15;
        int kbase = kc * 32 + (l >> 4) * 8;
        unsigned short* d = &wfrag[idx * 8];
#pragma unroll
        for (int j = 0; j < 8; j++) d[j] = Wb[(kbase + j) * 16 + n];
    }
    __syncthreads();

    int wave = tid >> 6, lane = tid & 63;
    int mrow = lane & 15, kq = lane >> 4;
    long row0 = (long)blockIdx.x * 64 + wave * 16;
    long row = row0 + mrow;
    bool valid = row < N;

    f32x4 acc = (f32x4){0.f, 0.f, 0.f, 0.f};
    for (int kc = 0; kc < 4; kc++) {
        bf16x8 a = {0, 0, 0, 0, 0, 0, 0, 0};
        if (valid) a = *(const bf16x8*)(A + row * 128 + kc * 32 + kq * 8);
        bf16x8 b = *(const bf16x8*)(&wfrag[(kc * 64 + lane) * 8]);
        acc = __builtin_amdgcn_mfma_f32_16x16x32_bf16(a, b, acc, 0, 0, 0);
    }
#pragma unroll
    for (int r = 0; r < 4; r++) {
        long orow = row0 + kq * 4 + r;
        if (orow < N) ht[orow * 16 + mrow] = f2bf(acc[r] * dinv[orow]);
    }
}

// ---- layer-1 gather: wave/node, uint4 loads; per-src dinv scale (fma); bias+relu
__global__ __launch_bounds__(256) void k_gather128(
    const unsigned short* __restrict__ h1t, const int* __restrict__ row_start,
    const int* __restrict__ deg_i, const float* __restrict__ dinv,
    const float* __restrict__ bb1, const int* __restrict__ adj,
    unsigned short* __restrict__ h1b, int N)
{
    int tid = threadIdx.x;
    int wave = tid >> 6, lane = tid & 63;
    int n = blockIdx.x * 4 + wave;
    if (n >= N) return;
    int g = lane >> 4, c = lane & 15;
    int cnt = deg_i[n];
    int start = row_start[n];
    int L = cnt + 1;                       // virtual list: neighbors + self at j==cnt

    float ac[8];
#pragma unroll
    for (int k = 0; k < 8; k++) ac[k] = 0.f;

    for (int jb = 0; jb < L; jb += 64) {
        int idx = jb + lane;
        int av = (idx < cnt) ? adj[start + idx] : n;
        int take = min(L - jb, 64);
        for (int jj = 0; jj < take; jj += 8) {
            int r0 = __shfl(av, jj + g);
            int r1 = __shfl(av, jj + 4 + g);
            bool m0 = (jj + g) < take;
            bool m1 = (jj + 4 + g) < take;
            float d0 = dinv[r0];           // L2-resident broadcast (r always valid id)
            float d1 = dinv[r1];
            uint4 v0 = make_uint4(0, 0, 0, 0), v1 = make_uint4(0, 0, 0, 0);
            if (m0) v0 = *(const uint4*)(h1t + (long)r0 * 128 + c * 8);
            if (m1) v1 = *(const uint4*)(h1t + (long)r1 * 128 + c * 8);
            acc8s(ac, v0, d0);
            acc8s(ac, v1, d1);
        }
    }
#pragma unroll
    for (int k = 0; k < 8; k++) {
        ac[k] += __shfl_xor(ac[k], 16);
        ac[k] += __shfl_xor(ac[k], 32);
    }
    if (g == 0) {
        float dv = dinv[n];
        float4 bA = *(const float4*)(bb1 + c * 8);
        float4 bB = *(const float4*)(bb1 + c * 8 + 4);
        float h0 = fmaxf(ac[0] * dv + bA.x, 0.f);
        float h1 = fmaxf(ac[1] * dv + bA.y, 0.f);
        float h2 = fmaxf(ac[2] * dv + bA.z, 0.f);
        float h3 = fmaxf(ac[3] * dv + bA.w, 0.f);
        float h4 = fmaxf(ac[4] * dv + bB.x, 0.f);
        float h5 = fmaxf(ac[5] * dv + bB.y, 0.f);
        float h6 = fmaxf(ac[6] * dv + bB.z, 0.f);
        float h7 = fmaxf(ac[7] * dv + bB.w, 0.f);
        uint4 pv;
        pv.x = (unsigned)f2bf(h0) | ((unsigned)f2bf(h1) << 16);
        pv.y = (unsigned)f2bf(h2) | ((unsigned)f2bf(h3) << 16);
        pv.z = (unsigned)f2bf(h4) | ((unsigned)f2bf(h5) << 16);
        pv.w = (unsigned)f2bf(h6) | ((unsigned)f2bf(h7) << 16);
        *(uint4*)(h1b + (long)n * 128 + c * 8) = pv;
    }
}

// ---- layer-2 gather + log_softmax: one node per LANE-PAIR (32 nodes/wave)
__global__ __launch_bounds__(256) void k_gather16(
    const unsigned short* __restrict__ h2t, const int* __restrict__ row_start,
    const int* __restrict__ deg_i, const float* __restrict__ dinv,
    const float* __restrict__ bb2, const int* __restrict__ adj,
    void* __restrict__ out, int N, const int* __restrict__ flags)
{
    int tid = threadIdx.x;
    int wave = tid >> 6, lane = tid & 63;
    int half = lane & 1;
    int n = (blockIdx.x * 4 + wave) * 32 + (lane >> 1);
    bool valid = n < N;
    int cnt = valid ? deg_i[n] : 0;
    int start = valid ? row_start[n] : 0;

    float ac[8];
#pragma unroll
    for (int k = 0; k < 8; k++) ac[k] = 0.f;

    int j = 0;
    for (; j + 2 <= cnt; j += 2) {
        int s0 = adj[start + j];
        int s1 = adj[start + j + 1];
        uint4 v0 = *(const uint4*)(h2t + (long)s0 * 16 + half * 8);
        uint4 v1 = *(const uint4*)(h2t + (long)s1 * 16 + half * 8);
        acc8(ac, v0);
        acc8(ac, v1);
    }
    if (j < cnt) {
        int s = adj[start + j];
        uint4 v = *(const uint4*)(h2t + (long)s * 16 + half * 8);
        acc8(ac, v);
    }
    if (!valid) return;
    {   // self-loop
        uint4 v = *(const uint4*)(h2t + (long)n * 16 + half * 8);
        acc8(ac, v);
    }
    float dv = dinv[n];
    float4 bA = *(const float4*)(bb2 + half * 8);
    float4 bB = *(const float4*)(bb2 + half * 8 + 4);
    float vv[8];
    vv[0] = ac[0] * dv + bA.x; vv[1] = ac[1] * dv + bA.y;
    vv[2] = ac[2] * dv + bA.z; vv[3] = ac[3] * dv + bA.w;
    vv[4] = ac[4] * dv + bB.x; vv[5] = ac[5] * dv + bB.y;
    vv[6] = ac[6] * dv + bB.z; vv[7] = ac[7] * dv + bB.w;
    float m8 = vv[0];
#pragma unroll
    for (int k = 1; k < 8; k++) m8 = fmaxf(m8, vv[k]);
    float m16 = fmaxf(m8, __shfl_xor(m8, 1));
    float s8 = 0.f;
#pragma unroll
    for (int k = 0; k < 8; k++) s8 += __expf(vv[k] - m16);
    float s16 = s8 + __shfl_xor(s8, 1);
    float lg = __logf(s16);
    if (flags[0]) {
        float* o = (float*)out + (long)n * 16 + half * 8;
        *(float4*)o = make_float4(vv[0] - m16 - lg, vv[1] - m16 - lg, vv[2] - m16 - lg, vv[3] - m16 - lg);
        *(float4*)(o + 4) = make_float4(vv[4] - m16 - lg, vv[5] - m16 - lg, vv[6] - m16 - lg, vv[7] - m16 - lg);
    } else {
        uint4 pv;
        pv.x = (unsigned)f2bf(vv[0] - m16 - lg) | ((unsigned)f2bf(vv[1] - m16 - lg) << 16);
        pv.y = (unsigned)f2bf(vv[2] - m16 - lg) | ((unsigned)f2bf(vv[3] - m16 - lg) << 16);
        pv.z = (unsigned)f2bf(vv[4] - m16 - lg) | ((unsigned)f2bf(vv[5] - m16 - lg) << 16);
        pv.w = (unsigned)f2bf(vv[6] - m16 - lg) | ((unsigned)f2bf(vv[7] - m16 - lg) << 16);
        *(uint4*)((unsigned short*)out + (long)n * 16 + half * 8) = pv;
    }
}

static inline size_t alignup(size_t x) { return (x + 255) & ~(size_t)255; }

extern "C" void kernel_launch(void* const* d_in, const int* in_sizes, int n_in,
                              void* d_out, int out_size, void* d_ws, size_t ws_size,
                              hipStream_t stream) {
    const void* xr  = d_in[0];
    const void* ei  = d_in[1];
    const void* W1r = d_in[2];
    const void* b1r = d_in[3];
    const void* W2r = d_in[4];
    const void* b2r = d_in[5];

    int N = in_sizes[0] / 128;
    int E = in_sizes[1] / 2;
    int NB = (N + 255) >> 8;

    char* w = (char*)d_ws;
    size_t off = 0;
    int*   flags = (int*)(w + off);   off += 256;      // flags[0..1]; gctr at flags[16]
    int*   gctr  = flags + 16;
    int*   deg_i = (int*)(w + off);   off = alignup(off + (size_t)N * 4);
    int*   row_start = (int*)(w + off); off = alignup(off + (size_t)N * 4);
    float* dinv  = (float*)(w + off); off = alignup(off + (size_t)N * 4);
    float* bb1   = (float*)(w + off); off = alignup(off + 128 * 4);
    float* bb2   = (float*)(w + off); off = alignup(off + 16 * 4);
    unsigned short* Wb1 = (unsigned short*)(w + off); off = alignup(off + 16384 * 2);
    unsigned short* Wb2 = (unsigned short*)(w + off); off = alignup(off + 2048 * 2);
    int*   bin_cnt = (int*)(w + off); off = alignup(off + (size_t)NB * 4);
    int*   adj   = (int*)(w + off);   off = alignup(off + (size_t)E * 4);
    unsigned short* h1t = (unsigned short*)(w + off); off = alignup(off + (size_t)N * 128 * 2);
    unsigned short* h1b = (unsigned short*)(w + off); off = alignup(off + (size_t)N * 128 * 2);
    unsigned short* h2t = (unsigned short*)(w + off); off = alignup(off + (size_t)N * 16 * 2);
    int* bin = (int*)h1b;   // overlay: bin (12.8 MB) dead before gather128 writes h1b

    int gG = (N + 63) / 64;
    int gA = (E + 4095) / 4096;
    int gW = (N + 3) / 4;
    int gP = (N + 127) / 128;

    k_setup<<<75, 256, 0, stream>>>(W1r, W2r, b1r, b2r, (const unsigned int*)ei,
                                    Wb1, Wb2, bb1, bb2, bin_cnt, gctr, flags, NB);
    k_front<<<gA + gG, 256, 0, stream>>>(ei, bin_cnt, bin, E, NB, flags,
                                         xr, Wb1, h1t, N, gA);
    k_binB<<<NB, 256, 0, stream>>>(bin_cnt, bin, deg_i, row_start, dinv, adj, gctr, N);

    k_gather128<<<gW, 256, 0, stream>>>(h1t, row_start, deg_i, dinv, bb1, adj, h1b, N);
    k_gemm2<<<gG, 256, 0, stream>>>(h1b, Wb2, dinv, h2t, N);
    k_gather16<<<gP, 256, 0, stream>>>(h2t, row_start, deg_i, dinv, bb2, adj, d_out, N, flags);
}